// Round 9
// baseline (3053.632 us; speedup 1.0000x reference)
//
#include <hip/hip_runtime.h>
#include <hip/hip_fp16.h>
#include <math.h>

#define BN 50000
#define BE 800000
#define CHUNK 104              // target edges per wave
#define NWAVES 7693            // ceil(BE/CHUNK)

typedef _Float16 h2 __attribute__((ext_vector_type(2)));

__device__ __forceinline__ float relu_f(float v) { return fmaxf(v, 0.0f); }
__device__ __forceinline__ float inv_clean(float s) {
    float q = 1.0f / s;
    return isfinite(q) ? q : 0.0f;
}
__device__ __forceinline__ float inv_clean_fast(float s) {
    float q = __builtin_amdgcn_rcpf(s);
    return isfinite(q) ? q : 0.0f;
}
__device__ __forceinline__ float fdot2f(h2 a, h2 b, float c) {
    return __builtin_amdgcn_fdot2(a, b, c, false);
}
__device__ __forceinline__ unsigned int h2u(h2 v) { union { h2 h; unsigned int u; } x; x.h = v; return x.u; }
__device__ __forceinline__ h2 uh2(unsigned int v) { union { unsigned int u; h2 h; } x; x.u = v; return x.h; }
__device__ __forceinline__ unsigned int packh2(float a, float b) {
    h2 h; h.x = (_Float16)a; h.y = (_Float16)b; return h2u(h);
}
// VALU-pipe broadcast of another lane's register (replaces LDS broadcast reads)
__device__ __forceinline__ unsigned int rl(unsigned int v, int lane) {
    return (unsigned int)__builtin_amdgcn_readlane((int)v, lane);
}

// ===========================================================================
// Weight packing (outputs in d_out head; k_node_final overwrites d_out last)
// ===========================================================================
__global__ __launch_bounds__(256) void k_pack_w1(
    const float* __restrict__ W, int r0, float4* __restrict__ dst)
{
    int t = blockIdx.x * 256 + threadIdx.x;
    if (t >= 2048) return;
    int j2 = t >> 6, l = t & 63;
    const float* ra = W + (size_t)(r0 + 2*j2) * 128 + 2*l;
    const float* rb = W + (size_t)(r0 + 2*j2 + 1) * 128 + 2*l;
    dst[t] = make_float4(ra[0], ra[1], rb[0], rb[1]);
}
__global__ __launch_bounds__(256) void k_pack_uv(
    const float* __restrict__ dW1, float4* __restrict__ dst)
{
    int t = blockIdx.x * 256 + threadIdx.x;
    if (t >= 4096) return;
    int j = t >> 6, l = t & 63;
    float4 w;
    if (l < 32) w = ((const float4*)(dW1 + (size_t)j*128))[l];
    else        w = ((const float4*)(dW1 + (size_t)(64+j)*128))[l-32];
    dst[t] = w;
}
__global__ __launch_bounds__(256) void k_pack_w1h(
    const float* __restrict__ W, int r0, uint2* __restrict__ dst)
{
    int t = blockIdx.x * 256 + threadIdx.x;
    if (t >= 2048) return;
    int j2 = t >> 6, l = t & 63;
    const float* ra = W + (size_t)(r0 + 2*j2) * 128;
    const float* rb = W + (size_t)(r0 + 2*j2 + 1) * 128;
    dst[t] = make_uint2(packh2(ra[2*l],   rb[2*l]),
                        packh2(ra[2*l+1], rb[2*l+1]));
}
__global__ __launch_bounds__(256) void k_pack_w2h(
    const float* __restrict__ W2, uint2* __restrict__ dst)
{
    int t = blockIdx.x * 256 + threadIdx.x;
    if (t >= 2048) return;
    int k4 = t >> 6, l = t & 63;
    dst[t] = make_uint2(packh2(W2[(4*k4+0)*64+l], W2[(4*k4+1)*64+l]),
                        packh2(W2[(4*k4+2)*64+l], W2[(4*k4+3)*64+l]));
}

// ===========================================================================
// CSR-ish build
// ===========================================================================
__global__ __launch_bounds__(256) void k_hist(
    const int* __restrict__ ei, int* __restrict__ rc, int* __restrict__ cc)
{
    int e = blockIdx.x * 256 + threadIdx.x;
    if (e >= BE) return;
    atomicAdd(&rc[ei[e]], 1);
    atomicAdd(&cc[ei[BE + e]], 1);
}

__global__ __launch_bounds__(1024) void k_scan(
    const int* __restrict__ cntR, int* __restrict__ hdR,
    const int* __restrict__ cntC, int* __restrict__ hdC)
{
    __shared__ int s[1024];
    const int* cnt; int* hd;
    if (blockIdx.x == 0) { cnt = cntR; hd = hdR; }
    else                 { cnt = cntC; hd = hdC; }
    int t = threadIdx.x;
    int base = t * 49;
    int sum = 0;
    for (int i = 0; i < 49; i++) {
        int idx = base + i;
        sum += (idx < BN) ? cnt[idx] : 0;
    }
    s[t] = sum;
    __syncthreads();
    for (int o = 1; o < 1024; o <<= 1) {
        int v = (t >= o) ? s[t - o] : 0;
        __syncthreads();
        s[t] += v;
        __syncthreads();
    }
    int run = s[t] - sum;
    for (int i = 0; i < 49; i++) {
        int idx = base + i;
        if (idx < BN) { hd[idx] = run; run += cnt[idx]; }
    }
}

__global__ __launch_bounds__(256) void k_scatter2(
    const int* __restrict__ ei, const float* __restrict__ ea,
    int* __restrict__ rhd, int* __restrict__ chd,
    int4* __restrict__ rs, int4* __restrict__ cs)
{
    int e = blockIdx.x * 256 + threadIdx.x;
    if (e >= BE) return;
    int r = ei[e], c = ei[BE + e];
    float2 s = ((const float2*)ea)[e];
    int s0 = __float_as_int(s.x), s1 = __float_as_int(s.y);
    int p1 = atomicAdd(&rhd[r], 1);
    rs[p1] = make_int4(r, c, s0, s1);
    int p2 = atomicAdd(&chd[c], 1);
    cs[p2] = make_int4(c, r, s0, s1);
}

// sumsp from sorted records (hd = end offsets after scatter)
__global__ __launch_bounds__(256) void k_sumsp2(
    const int4* __restrict__ rs, const int* __restrict__ rhd, const int* __restrict__ rcnt,
    const int4* __restrict__ cs, const int* __restrict__ chd, const int* __restrict__ ccnt,
    float* __restrict__ sumsp)
{
    int n = blockIdx.x * 256 + threadIdx.x;
    if (n >= BN) return;
    float s0 = 0.f, s1 = 0.f;
    int e1 = rhd[n], e0 = e1 - rcnt[n];
    for (int j = e0; j < e1; j++) {
        int4 rec = rs[j];
        s0 += __int_as_float(rec.z); s1 += __int_as_float(rec.w);
    }
    e1 = chd[n]; e0 = e1 - ccnt[n];
    for (int j = e0; j < e1; j++) {
        int4 rec = cs[j];
        s0 += __int_as_float(rec.z); s1 += __int_as_float(rec.w);
    }
    sumsp[2*n]   = s0;
    sumsp[2*n+1] = s1;
}

// Node-aligned wave partition: lb[w] = first node whose start offset >= w*CHUNK.
__global__ __launch_bounds__(256) void k_part(
    const int* __restrict__ rhd, const int* __restrict__ rcnt, int* __restrict__ lbr,
    const int* __restrict__ chd, const int* __restrict__ ccnt, int* __restrict__ lbc)
{
    int t = blockIdx.x * 256 + threadIdx.x;
    if (t >= 2 * (NWAVES + 1)) return;
    int which = (t > NWAVES) ? 1 : 0;
    int w = t - which * (NWAVES + 1);
    const int* hd  = which ? chd  : rhd;
    const int* cnt = which ? ccnt : rcnt;
    int* lb        = which ? lbc  : lbr;
    if (w == NWAVES) { lb[NWAVES] = BN; return; }
    int target = w * CHUNK;
    int lo = 0, hi = BN;
    while (lo < hi) {
        int mid = (lo + hi) >> 1;
        int s = hd[mid] - cnt[mid];       // start offset of node mid
        if (s >= target) hi = mid; else lo = mid + 1;
    }
    lb[w] = lo;
}

// ===========================================================================
// k_uvh: fused node-enc + uv GEMM; outputs u,v in fp16
// ===========================================================================
__global__ __launch_bounds__(256, 6) void k_uvh(
    const float* __restrict__ x,
    const float* __restrict__ enW, const float* __restrict__ enB,
    const float4* __restrict__ guv,
    __half* __restrict__ u_h, __half* __restrict__ v_h)
{
    extern __shared__ float lds[];
    const int wid = threadIdx.x >> 6, l = threadIdx.x & 63;
    float4* xb4 = (float4*)(lds + wid * 512);
    const int gw = blockIdx.x * 4 + wid;
    const int nw = gridDim.x * 4;

    const int jj = l & 31;
    const float w0a = enW[jj],    w0b = enW[64+jj],  b0 = enB[jj];
    const float w1a = enW[jj+32], w1b = enW[96+jj],  b1 = enB[jj+32];

    for (int g = gw; g < BN/8; g += nw) {
        const int n0 = g * 8;
        const int q = l >> 5;
        {
            float2 xa = ((const float2*)x)[n0 + q*4 + 0];
            float2 xb = ((const float2*)x)[n0 + q*4 + 1];
            float2 xc = ((const float2*)x)[n0 + q*4 + 2];
            float2 xd = ((const float2*)x)[n0 + q*4 + 3];
            float4 p0, p1;
            p0.x = relu_f(fmaf(xa.x, w0a, fmaf(xa.y, w0b, b0)));
            p0.y = relu_f(fmaf(xb.x, w0a, fmaf(xb.y, w0b, b0)));
            p0.z = relu_f(fmaf(xc.x, w0a, fmaf(xc.y, w0b, b0)));
            p0.w = relu_f(fmaf(xd.x, w0a, fmaf(xd.y, w0b, b0)));
            p1.x = relu_f(fmaf(xa.x, w1a, fmaf(xa.y, w1b, b1)));
            p1.y = relu_f(fmaf(xb.x, w1a, fmaf(xb.y, w1b, b1)));
            p1.z = relu_f(fmaf(xc.x, w1a, fmaf(xc.y, w1b, b1)));
            p1.w = relu_f(fmaf(xd.x, w1a, fmaf(xd.y, w1b, b1)));
            xb4[jj*2 + q]      = p0;
            xb4[(jj+32)*2 + q] = p1;
        }
        float4 acc[8];
        #pragma unroll
        for (int e = 0; e < 8; e++) acc[e] = make_float4(0,0,0,0);
        #pragma unroll 8
        for (int j = 0; j < 64; j++) {
            float4 wq = guv[j*64 + l];
            float4 xa = xb4[j*2 + 0];
            float4 xc = xb4[j*2 + 1];
            acc[0].x = fmaf(xa.x, wq.x, acc[0].x); acc[0].y = fmaf(xa.x, wq.y, acc[0].y);
            acc[0].z = fmaf(xa.x, wq.z, acc[0].z); acc[0].w = fmaf(xa.x, wq.w, acc[0].w);
            acc[1].x = fmaf(xa.y, wq.x, acc[1].x); acc[1].y = fmaf(xa.y, wq.y, acc[1].y);
            acc[1].z = fmaf(xa.y, wq.z, acc[1].z); acc[1].w = fmaf(xa.y, wq.w, acc[1].w);
            acc[2].x = fmaf(xa.z, wq.x, acc[2].x); acc[2].y = fmaf(xa.z, wq.y, acc[2].y);
            acc[2].z = fmaf(xa.z, wq.z, acc[2].z); acc[2].w = fmaf(xa.z, wq.w, acc[2].w);
            acc[3].x = fmaf(xa.w, wq.x, acc[3].x); acc[3].y = fmaf(xa.w, wq.y, acc[3].y);
            acc[3].z = fmaf(xa.w, wq.z, acc[3].z); acc[3].w = fmaf(xa.w, wq.w, acc[3].w);
            acc[4].x = fmaf(xc.x, wq.x, acc[4].x); acc[4].y = fmaf(xc.x, wq.y, acc[4].y);
            acc[4].z = fmaf(xc.x, wq.z, acc[4].z); acc[4].w = fmaf(xc.x, wq.w, acc[4].w);
            acc[5].x = fmaf(xc.y, wq.x, acc[5].x); acc[5].y = fmaf(xc.y, wq.y, acc[5].y);
            acc[5].z = fmaf(xc.y, wq.z, acc[5].z); acc[5].w = fmaf(xc.y, wq.w, acc[5].w);
            acc[6].x = fmaf(xc.z, wq.x, acc[6].x); acc[6].y = fmaf(xc.z, wq.y, acc[6].y);
            acc[6].z = fmaf(xc.z, wq.z, acc[6].z); acc[6].w = fmaf(xc.z, wq.w, acc[6].w);
            acc[7].x = fmaf(xc.w, wq.x, acc[7].x); acc[7].y = fmaf(xc.w, wq.y, acc[7].y);
            acc[7].z = fmaf(xc.w, wq.z, acc[7].z); acc[7].w = fmaf(xc.w, wq.w, acc[7].w);
        }
        __half* dst = (l < 32) ? (u_h + 4*l) : (v_h + 4*(l-32));
        #pragma unroll
        for (int e = 0; e < 8; e++) {
            __half2* p = (__half2*)(dst + (size_t)(n0+e)*128);
            p[0] = __floats2half2_rn(acc[e].x, acc[e].y);
            p[1] = __floats2half2_rn(acc[e].z, acc[e].w);
        }
    }
}

// ===========================================================================
// k_e1: pass-1 one-sided, node-aligned partition, plain stores, NO LDS:
// all cross-lane broadcasts via v_readlane (VALU pipe) — round-9 change.
// ===========================================================================
__global__ __launch_bounds__(256, 4) void k_e1(
    const int4* __restrict__ recs,
    const __half* __restrict__ A_h, const __half* __restrict__ B_h,
    const int* __restrict__ lb, const int* __restrict__ hd, const int* __restrict__ cnt,
    const float* __restrict__ e2w, const float* __restrict__ e2b,
    const uint2* __restrict__ pw1, const float* __restrict__ db1,
    const uint2* __restrict__ pw2, const float* __restrict__ db2,
    float* __restrict__ outAcc)
{
    const int l = threadIdx.x & 63;
    const int wid = threadIdx.x >> 6;

    const int wave = blockIdx.x * 4 + wid;
    if (wave >= NWAVES) return;
    const int n0 = lb[wave], n1 = lb[wave + 1];
    if (n0 >= n1) return;
    const int eb = hd[n0] - cnt[n0];
    const int ee = (n1 < BN) ? (hd[n1] - cnt[n1]) : BE;
    if (eb >= ee) return;

    const int j2 = l >> 1, eh = l & 1;
    const float w0a = e2w[2*j2],    w0b = e2w[64+2*j2], eb0 = e2b[2*j2];
    const float w1a = e2w[2*j2+1],  w1b = e2w[65+2*j2], eb1 = e2b[2*j2+1];
    const float b1a = db1[2*l], b1b = db1[2*l+1];
    const float b2r = db2[l];

    float acc = 0.f;
    int cur = -1;

    for (int i = eb; i < ee; i += 8) {
        const int nact = min(8, ee - i);
        int key[8], oth[8];
        float spx[8], spy[8];
        #pragma unroll
        for (int e = 0; e < 8; e++) {
            int idx = i + ((e < nact) ? e : nact - 1);
            int4 rec = recs[idx];
            key[e] = rec.x; oth[e] = rec.y;
            spx[e] = __int_as_float(rec.z); spy[e] = __int_as_float(rec.w);
        }
        // ise rows (2j2, 2j2+1) for edges 4eh..4eh+3, kept in registers
        uint4 xw;
        {
            unsigned int* xp = (unsigned int*)&xw;
            #pragma unroll
            for (int c = 0; c < 4; c++) {
                int e = 4*eh + c;
                float q0 = inv_clean_fast(spx[e]);
                float q1 = inv_clean_fast(spy[e]);
                float r0 = relu_f(fmaf(q0, w0a, fmaf(q1, w0b, eb0)));
                float r1 = relu_f(fmaf(q0, w1a, fmaf(q1, w1b, eb1)));
                xp[c] = packh2(r0, r1);
            }
        }
        // t init = b1 + A[key] + B[oth]
        float t0[8], t1[8];
        #pragma unroll
        for (int e = 0; e < 8; e++) {
            float2 au = __half22float2(*(const __half2*)(A_h + (size_t)key[e]*128 + 2*l));
            float2 bu = __half22float2(*(const __half2*)(B_h + (size_t)oth[e]*128 + 2*l));
            t0[e] = b1a + au.x + bu.x;
            t1[e] = b1b + au.y + bu.y;
        }
        // layer-1: broadcast lanes (2p, 2p+1)'s xw via readlane
        #pragma unroll 8
        for (int p = 0; p < 32; p++) {
            unsigned x0x = rl(xw.x, 2*p),   x0y = rl(xw.y, 2*p);
            unsigned x0z = rl(xw.z, 2*p),   x0w = rl(xw.w, 2*p);
            unsigned x1x = rl(xw.x, 2*p+1), x1y = rl(xw.y, 2*p+1);
            unsigned x1z = rl(xw.z, 2*p+1), x1w = rl(xw.w, 2*p+1);
            uint2 wv = pw1[p*64 + l];
            h2 wa = uh2(wv.x), wb = uh2(wv.y);
            t0[0] = fdot2f(uh2(x0x), wa, t0[0]); t1[0] = fdot2f(uh2(x0x), wb, t1[0]);
            t0[1] = fdot2f(uh2(x0y), wa, t0[1]); t1[1] = fdot2f(uh2(x0y), wb, t1[1]);
            t0[2] = fdot2f(uh2(x0z), wa, t0[2]); t1[2] = fdot2f(uh2(x0z), wb, t1[2]);
            t0[3] = fdot2f(uh2(x0w), wa, t0[3]); t1[3] = fdot2f(uh2(x0w), wb, t1[3]);
            t0[4] = fdot2f(uh2(x1x), wa, t0[4]); t1[4] = fdot2f(uh2(x1x), wb, t1[4]);
            t0[5] = fdot2f(uh2(x1y), wa, t0[5]); t1[5] = fdot2f(uh2(x1y), wb, t1[5]);
            t0[6] = fdot2f(uh2(x1z), wa, t0[6]); t1[6] = fdot2f(uh2(x1z), wb, t1[6]);
            t0[7] = fdot2f(uh2(x1w), wa, t0[7]); t1[7] = fdot2f(uh2(x1w), wb, t1[7]);
        }
        // h (channels 2l,2l+1, 8 edges) in registers
        uint4 hA, hB;
        {
            unsigned int* pa = (unsigned int*)&hA;
            unsigned int* pb = (unsigned int*)&hB;
            #pragma unroll
            for (int c = 0; c < 4; c++) {
                pa[c] = packh2(relu_f(t0[c]),   relu_f(t1[c]));
                pb[c] = packh2(relu_f(t0[4+c]), relu_f(t1[4+c]));
            }
        }
        // layer-2: broadcast lanes (2k4, 2k4+1)'s hA/hB via readlane
        float o[8] = {0,0,0,0,0,0,0,0};
        #pragma unroll 8
        for (int k4 = 0; k4 < 32; k4++) {
            unsigned a0x = rl(hA.x, 2*k4),   a0y = rl(hA.y, 2*k4);
            unsigned a0z = rl(hA.z, 2*k4),   a0w = rl(hA.w, 2*k4);
            unsigned a1x = rl(hB.x, 2*k4),   a1y = rl(hB.y, 2*k4);
            unsigned a1z = rl(hB.z, 2*k4),   a1w = rl(hB.w, 2*k4);
            unsigned b0x = rl(hA.x, 2*k4+1), b0y = rl(hA.y, 2*k4+1);
            unsigned b0z = rl(hA.z, 2*k4+1), b0w = rl(hA.w, 2*k4+1);
            unsigned b1x = rl(hB.x, 2*k4+1), b1y = rl(hB.y, 2*k4+1);
            unsigned b1z = rl(hB.z, 2*k4+1), b1w = rl(hB.w, 2*k4+1);
            uint2 wv = pw2[k4*64 + l];
            h2 wa = uh2(wv.x), wb = uh2(wv.y);
            o[0] = fdot2f(uh2(b0x), wb, fdot2f(uh2(a0x), wa, o[0]));
            o[1] = fdot2f(uh2(b0y), wb, fdot2f(uh2(a0y), wa, o[1]));
            o[2] = fdot2f(uh2(b0z), wb, fdot2f(uh2(a0z), wa, o[2]));
            o[3] = fdot2f(uh2(b0w), wb, fdot2f(uh2(a0w), wa, o[3]));
            o[4] = fdot2f(uh2(b1x), wb, fdot2f(uh2(a1x), wa, o[4]));
            o[5] = fdot2f(uh2(b1y), wb, fdot2f(uh2(a1y), wa, o[5]));
            o[6] = fdot2f(uh2(b1z), wb, fdot2f(uh2(a1z), wa, o[6]));
            o[7] = fdot2f(uh2(b1w), wb, fdot2f(uh2(a1w), wa, o[7]));
        }
        #pragma unroll
        for (int e = 0; e < 8; e++) {
            if (e < nact) {
                float val = o[e] + b2r;
                if (key[e] != cur) {
                    if (cur >= 0) outAcc[(size_t)cur*64 + l] = acc;   // plain store
                    acc = 0.f;
                    cur = key[e];
                }
                acc += val;
            }
        }
    }
    if (cur >= 0) outAcc[(size_t)cur*64 + l] = acc;
}

// ===========================================================================
// k_tptmh: tp[n] = hjp[n] @ hW1[64:128,:], tm[n] = hjm[n] @ hW1[64:128,:]  (fp16 out)
// ===========================================================================
__global__ __launch_bounds__(256, 6) void k_tptmh(
    const float* __restrict__ hjp, const float* __restrict__ hjm,
    const float4* __restrict__ gtp,
    __half* __restrict__ tp_h, __half* __restrict__ tm_h)
{
    extern __shared__ float lds[];
    const int wid = threadIdx.x >> 6, l = threadIdx.x & 63;
    float4* xb4 = (float4*)(lds + wid * 512);
    const int gw = blockIdx.x * 4 + wid;
    const int nw = gridDim.x * 4;
    const int NG = BN/8;

    for (int vg = gw; vg < 2*NG; vg += nw) {
        const float* in = (vg < NG) ? hjp : hjm;
        __half*     out = (vg < NG) ? tp_h : tm_h;
        const int n0 = ((vg < NG) ? vg : vg - NG) * 8;
        const int q = l >> 5;
        #pragma unroll
        for (int r = 0; r < 2; r++) {
            int j = (l & 31) + 32*r;
            float v0 = in[(n0 + q*4 + 0)*64 + j];
            float v1 = in[(n0 + q*4 + 1)*64 + j];
            float v2 = in[(n0 + q*4 + 2)*64 + j];
            float v3 = in[(n0 + q*4 + 3)*64 + j];
            xb4[j*2 + q] = make_float4(v0, v1, v2, v3);
        }
        float a0[8] = {0,0,0,0,0,0,0,0}, a1[8] = {0,0,0,0,0,0,0,0};
        #pragma unroll 8
        for (int j2 = 0; j2 < 32; j2++) {
            float4 wq = gtp[j2*64 + l];
            float4 xa = xb4[(2*j2)*2 + 0];
            float4 xbv = xb4[(2*j2)*2 + 1];
            float4 xc = xb4[(2*j2+1)*2 + 0];
            float4 xd = xb4[(2*j2+1)*2 + 1];
            a0[0] = fmaf(xa.x, wq.x, fmaf(xc.x, wq.z, a0[0]));
            a1[0] = fmaf(xa.x, wq.y, fmaf(xc.x, wq.w, a1[0]));
            a0[1] = fmaf(xa.y, wq.x, fmaf(xc.y, wq.z, a0[1]));
            a1[1] = fmaf(xa.y, wq.y, fmaf(xc.y, wq.w, a1[1]));
            a0[2] = fmaf(xa.z, wq.x, fmaf(xc.z, wq.z, a0[2]));
            a1[2] = fmaf(xa.z, wq.y, fmaf(xc.z, wq.w, a1[2]));
            a0[3] = fmaf(xa.w, wq.x, fmaf(xc.w, wq.z, a0[3]));
            a1[3] = fmaf(xa.w, wq.y, fmaf(xc.w, wq.w, a1[3]));
            a0[4] = fmaf(xbv.x, wq.x, fmaf(xd.x, wq.z, a0[4]));
            a1[4] = fmaf(xbv.x, wq.y, fmaf(xd.x, wq.w, a1[4]));
            a0[5] = fmaf(xbv.y, wq.x, fmaf(xd.y, wq.z, a0[5]));
            a1[5] = fmaf(xbv.y, wq.y, fmaf(xd.y, wq.w, a1[5]));
            a0[6] = fmaf(xbv.z, wq.x, fmaf(xd.z, wq.z, a0[6]));
            a1[6] = fmaf(xbv.z, wq.y, fmaf(xd.z, wq.w, a1[6]));
            a0[7] = fmaf(xbv.w, wq.x, fmaf(xd.w, wq.z, a0[7]));
            a1[7] = fmaf(xbv.w, wq.y, fmaf(xd.w, wq.w, a1[7]));
        }
        #pragma unroll
        for (int e = 0; e < 8; e++) {
            *(__half2*)(out + (size_t)(n0+e)*128 + 2*l) = __floats2half2_rn(a0[e], a1[e]);
        }
    }
}

// ===========================================================================
// k_e2: pass-2, node-aligned partition, plain stores, NO LDS (readlane).
// ===========================================================================
__global__ __launch_bounds__(256, 4) void k_e2(
    const int4* __restrict__ recs, const __half* __restrict__ tvals_h,
    const int* __restrict__ lb, const int* __restrict__ hd, const int* __restrict__ cnt,
    const float* __restrict__ eew, const float* __restrict__ eeb,
    const uint2* __restrict__ pw1, const float* __restrict__ hb1,
    const uint2* __restrict__ pw2, const float* __restrict__ hb2,
    float* __restrict__ out)
{
    const int l = threadIdx.x & 63;
    const int wid = threadIdx.x >> 6;

    const int wave = blockIdx.x * 4 + wid;
    if (wave >= NWAVES) return;
    const int n0 = lb[wave], n1 = lb[wave + 1];
    if (n0 >= n1) return;
    const int eb = hd[n0] - cnt[n0];
    const int ee = (n1 < BN) ? (hd[n1] - cnt[n1]) : BE;
    if (eb >= ee) return;

    const int j2 = l >> 1, eh = l & 1;
    const float w0a = eew[2*j2],    w0b = eew[64+2*j2], eb0 = eeb[2*j2];
    const float w1a = eew[2*j2+1],  w1b = eew[65+2*j2], eb1 = eeb[2*j2+1];
    const float b1a = hb1[2*l], b1b = hb1[2*l+1];
    const float b2r = hb2[l];

    float acc = 0.f;
    int cur = -1;

    for (int i = eb; i < ee; i += 8) {
        const int nact = min(8, ee - i);
        int key[8];
        float spx[8], spy[8];
        #pragma unroll
        for (int e = 0; e < 8; e++) {
            int idx = i + ((e < nact) ? e : nact - 1);
            int4 rec = recs[idx];
            key[e] = rec.x;
            spx[e] = __int_as_float(rec.z); spy[e] = __int_as_float(rec.w);
        }
        uint4 xw;
        {
            unsigned int* xp = (unsigned int*)&xw;
            #pragma unroll
            for (int c = 0; c < 4; c++) {
                int e = 4*eh + c;
                float r0 = relu_f(fmaf(spx[e], w0a, fmaf(spy[e], w0b, eb0)));
                float r1 = relu_f(fmaf(spx[e], w1a, fmaf(spy[e], w1b, eb1)));
                xp[c] = packh2(r0, r1);
            }
        }
        float t0[8], t1[8];
        #pragma unroll
        for (int e = 0; e < 8; e++) {
            float2 tv = __half22float2(*(const __half2*)(tvals_h + (size_t)key[e]*128 + 2*l));
            t0[e] = b1a + tv.x;
            t1[e] = b1b + tv.y;
        }
        #pragma unroll 8
        for (int p = 0; p < 32; p++) {
            unsigned x0x = rl(xw.x, 2*p),   x0y = rl(xw.y, 2*p);
            unsigned x0z = rl(xw.z, 2*p),   x0w = rl(xw.w, 2*p);
            unsigned x1x = rl(xw.x, 2*p+1), x1y = rl(xw.y, 2*p+1);
            unsigned x1z = rl(xw.z, 2*p+1), x1w = rl(xw.w, 2*p+1);
            uint2 wv = pw1[p*64 + l];
            h2 wa = uh2(wv.x), wb = uh2(wv.y);
            t0[0] = fdot2f(uh2(x0x), wa, t0[0]); t1[0] = fdot2f(uh2(x0x), wb, t1[0]);
            t0[1] = fdot2f(uh2(x0y), wa, t0[1]); t1[1] = fdot2f(uh2(x0y), wb, t1[1]);
            t0[2] = fdot2f(uh2(x0z), wa, t0[2]); t1[2] = fdot2f(uh2(x0z), wb, t1[2]);
            t0[3] = fdot2f(uh2(x0w), wa, t0[3]); t1[3] = fdot2f(uh2(x0w), wb, t1[3]);
            t0[4] = fdot2f(uh2(x1x), wa, t0[4]); t1[4] = fdot2f(uh2(x1x), wb, t1[4]);
            t0[5] = fdot2f(uh2(x1y), wa, t0[5]); t1[5] = fdot2f(uh2(x1y), wb, t1[5]);
            t0[6] = fdot2f(uh2(x1z), wa, t0[6]); t1[6] = fdot2f(uh2(x1z), wb, t1[6]);
            t0[7] = fdot2f(uh2(x1w), wa, t0[7]); t1[7] = fdot2f(uh2(x1w), wb, t1[7]);
        }
        uint4 hA, hB;
        {
            unsigned int* pa = (unsigned int*)&hA;
            unsigned int* pb = (unsigned int*)&hB;
            #pragma unroll
            for (int c = 0; c < 4; c++) {
                pa[c] = packh2(relu_f(t0[c]),   relu_f(t1[c]));
                pb[c] = packh2(relu_f(t0[4+c]), relu_f(t1[4+c]));
            }
        }
        float o[8] = {0,0,0,0,0,0,0,0};
        #pragma unroll 8
        for (int k4 = 0; k4 < 32; k4++) {
            unsigned a0x = rl(hA.x, 2*k4),   a0y = rl(hA.y, 2*k4);
            unsigned a0z = rl(hA.z, 2*k4),   a0w = rl(hA.w, 2*k4);
            unsigned a1x = rl(hB.x, 2*k4),   a1y = rl(hB.y, 2*k4);
            unsigned a1z = rl(hB.z, 2*k4),   a1w = rl(hB.w, 2*k4);
            unsigned b0x = rl(hA.x, 2*k4+1), b0y = rl(hA.y, 2*k4+1);
            unsigned b0z = rl(hA.z, 2*k4+1), b0w = rl(hA.w, 2*k4+1);
            unsigned b1x = rl(hB.x, 2*k4+1), b1y = rl(hB.y, 2*k4+1);
            unsigned b1z = rl(hB.z, 2*k4+1), b1w = rl(hB.w, 2*k4+1);
            uint2 wv = pw2[k4*64 + l];
            h2 wa = uh2(wv.x), wb = uh2(wv.y);
            o[0] = fdot2f(uh2(b0x), wb, fdot2f(uh2(a0x), wa, o[0]));
            o[1] = fdot2f(uh2(b0y), wb, fdot2f(uh2(a0y), wa, o[1]));
            o[2] = fdot2f(uh2(b0z), wb, fdot2f(uh2(a0z), wa, o[2]));
            o[3] = fdot2f(uh2(b0w), wb, fdot2f(uh2(a0w), wa, o[3]));
            o[4] = fdot2f(uh2(b1x), wb, fdot2f(uh2(a1x), wa, o[4]));
            o[5] = fdot2f(uh2(b1y), wb, fdot2f(uh2(a1y), wa, o[5]));
            o[6] = fdot2f(uh2(b1z), wb, fdot2f(uh2(a1z), wa, o[6]));
            o[7] = fdot2f(uh2(b1w), wb, fdot2f(uh2(a1w), wa, o[7]));
        }
        #pragma unroll
        for (int e = 0; e < 8; e++) {
            if (e < nact) {
                float val = o[e] + b2r;
                if (key[e] != cur) {
                    if (cur >= 0) out[(size_t)cur*64 + l] = acc;      // plain store
                    acc = 0.f;
                    cur = key[e];
                }
                acc += val;
            }
        }
    }
    if (cur >= 0) out[(size_t)cur*64 + l] = acc;
}

// ===========================================================================
// Node MLP kernels (fp32, weights streamed from global)
// ===========================================================================
__global__ __launch_bounds__(256, 4) void k_node_mlp(
    const float* __restrict__ A, const float* __restrict__ Bv,
    const float* __restrict__ sumsp,
    const float* __restrict__ e2w_g, const float* __restrict__ e2b_g,
    const float* __restrict__ W1g, const float* __restrict__ b1g,
    const float* __restrict__ W2g, const float* __restrict__ b2g,
    float* __restrict__ outp)
{
    extern __shared__ float lds[];
    const int wid = threadIdx.x >> 6, l = threadIdx.x & 63;
    float* xbuf = lds + wid * 768;
    float* hbuf = lds + 4*768 + wid * 512;

    const float ewl = e2w_g[l], ewl2 = e2w_g[64+l], ebl = e2b_g[l];
    const float bb0 = b1g[2*l], bb1 = b1g[2*l+1];
    const float bo = b2g[l];

    const int gw = blockIdx.x * 4 + wid;
    const int nw = gridDim.x * 4;

    for (int g = gw; g < BN/4; g += nw) {
        const int i0 = g * 4;
        float av[4], bv[4], iv[4];
        #pragma unroll
        for (int e = 0; e < 4; e++) {
            int i = i0 + e;
            av[e] = A[i*64 + l];
            bv[e] = Bv[i*64 + l];
            float q0 = inv_clean(sumsp[i*2+0]);
            float q1 = inv_clean(sumsp[i*2+1]);
            iv[e] = relu_f(fmaf(q0, ewl, fmaf(q1, ewl2, ebl)));
        }
        ((float4*)xbuf)[l]       = make_float4(av[0], av[1], av[2], av[3]);
        ((float4*)xbuf)[64 + l]  = make_float4(bv[0], bv[1], bv[2], bv[3]);
        ((float4*)xbuf)[128 + l] = make_float4(iv[0], iv[1], iv[2], iv[3]);

        float acc0[4] = {0,0,0,0}, acc1[4] = {0,0,0,0};
        #pragma unroll 8
        for (int j = 0; j < 192; j++) {
            float4 xv = ((const float4*)xbuf)[j];
            float2 wv = ((const float2*)(W1g + j*128))[l];
            acc0[0] = fmaf(xv.x, wv.x, acc0[0]);
            acc0[1] = fmaf(xv.y, wv.x, acc0[1]);
            acc0[2] = fmaf(xv.z, wv.x, acc0[2]);
            acc0[3] = fmaf(xv.w, wv.x, acc0[3]);
            acc1[0] = fmaf(xv.x, wv.y, acc1[0]);
            acc1[1] = fmaf(xv.y, wv.y, acc1[1]);
            acc1[2] = fmaf(xv.z, wv.y, acc1[2]);
            acc1[3] = fmaf(xv.w, wv.y, acc1[3]);
        }
        #pragma unroll
        for (int e = 0; e < 4; e++) {
            ((float2*)(hbuf + e*128))[l] = make_float2(relu_f(acc0[e]+bb0), relu_f(acc1[e]+bb1));
        }
        float o[4] = {0,0,0,0};
        #pragma unroll 8
        for (int k = 0; k < 128; k++) {
            float wv = W2g[k*64 + l];
            o[0] = fmaf(hbuf[0*128+k], wv, o[0]);
            o[1] = fmaf(hbuf[1*128+k], wv, o[1]);
            o[2] = fmaf(hbuf[2*128+k], wv, o[2]);
            o[3] = fmaf(hbuf[3*128+k], wv, o[3]);
        }
        #pragma unroll
        for (int e = 0; e < 4; e++) outp[(i0+e)*64 + l] = o[e] + bo;
    }
}

__global__ __launch_bounds__(256, 4) void k_node_final(
    const float* __restrict__ x,
    const float* __restrict__ enW, const float* __restrict__ enB,
    const float* __restrict__ jacv, const float* __restrict__ hessv,
    const int* __restrict__ batch, const float* __restrict__ ga,
    const float* __restrict__ gw_g, const float* __restrict__ gb_g,
    const float* __restrict__ nW1, const float* __restrict__ nb1,
    const float* __restrict__ nW2, const float* __restrict__ nb2,
    const float* __restrict__ decW, const float* __restrict__ decb,
    const float* __restrict__ node_attr, float* __restrict__ outp)
{
    extern __shared__ float lds[];
    const int wid = threadIdx.x >> 6, l = threadIdx.x & 63;
    float* xbuf = lds + wid * 1024;
    float* hbuf = lds + 4*1024 + wid * 512;

    const float gwl = gw_g[l], gwl2 = gw_g[64+l], gbl = gb_g[l];
    const float enw0 = enW[l], enw1 = enW[64+l], enb = enB[l];
    const float bb0 = nb1[2*l], bb1 = nb1[2*l+1];
    const float bo = nb2[l];

    const int gwv = blockIdx.x * 4 + wid;
    const int nw = gridDim.x * 4;

    for (int g = gwv; g < BN/4; g += nw) {
        const int i0 = g * 4;
        float ne[4], jv[4], ge[4], hv[4];
        #pragma unroll
        for (int e = 0; e < 4; e++) {
            int i = i0 + e;
            ne[e] = relu_f(fmaf(x[i*2], enw0, fmaf(x[i*2+1], enw1, enb)));
            jv[e] = jacv[i*64 + l];
            hv[e] = hessv[i*64 + l];
            int gi = batch[i];
            ge[e] = relu_f(fmaf(ga[gi*2], gwl, fmaf(ga[gi*2+1], gwl2, gbl)));
        }
        ((float4*)xbuf)[l]       = make_float4(ne[0], ne[1], ne[2], ne[3]);
        ((float4*)xbuf)[64 + l]  = make_float4(jv[0], jv[1], jv[2], jv[3]);
        ((float4*)xbuf)[128 + l] = make_float4(ge[0], ge[1], ge[2], ge[3]);
        ((float4*)xbuf)[192 + l] = make_float4(hv[0], hv[1], hv[2], hv[3]);

        float acc0[4] = {0,0,0,0}, acc1[4] = {0,0,0,0};
        #pragma unroll 8
        for (int j = 0; j < 256; j++) {
            float4 xv = ((const float4*)xbuf)[j];
            float2 wv = ((const float2*)(nW1 + j*128))[l];
            acc0[0] = fmaf(xv.x, wv.x, acc0[0]);
            acc0[1] = fmaf(xv.y, wv.x, acc0[1]);
            acc0[2] = fmaf(xv.z, wv.x, acc0[2]);
            acc0[3] = fmaf(xv.w, wv.x, acc0[3]);
            acc1[0] = fmaf(xv.x, wv.y, acc1[0]);
            acc1[1] = fmaf(xv.y, wv.y, acc1[1]);
            acc1[2] = fmaf(xv.z, wv.y, acc1[2]);
            acc1[3] = fmaf(xv.w, wv.y, acc1[3]);
        }
        #pragma unroll
        for (int e = 0; e < 4; e++) {
            ((float2*)(hbuf + e*128))[l] = make_float2(relu_f(acc0[e]+bb0), relu_f(acc1[e]+bb1));
        }
        float o[4] = {0,0,0,0};
        #pragma unroll 8
        for (int k = 0; k < 128; k++) {
            float wv = nW2[k*64 + l];
            o[0] = fmaf(hbuf[0*128+k], wv, o[0]);
            o[1] = fmaf(hbuf[1*128+k], wv, o[1]);
            o[2] = fmaf(hbuf[2*128+k], wv, o[2]);
            o[3] = fmaf(hbuf[3*128+k], wv, o[3]);
        }
        #pragma unroll
        for (int e = 0; e < 4; e++) hbuf[e*128 + l] = o[e] + bo;

        int e2 = l >> 4, sub = l & 15, j2 = sub >> 3, part = sub & 7;
        float s = 0.0f;
        #pragma unroll
        for (int kk = 0; kk < 8; kk++) {
            int k = part*8 + kk;
            s = fmaf(hbuf[e2*128 + k], decW[k*2 + j2], s);
        }
        s += __shfl_xor(s, 1);
        s += __shfl_xor(s, 2);
        s += __shfl_xor(s, 4);
        if (part == 0) {
            int i = i0 + e2;
            outp[i*2 + j2] = (s + decb[j2]) * node_attr[i*2 + j2];
        }
    }
}

// ===========================================================================
extern "C" void kernel_launch(void* const* d_in, const int* in_sizes, int n_in,
                              void* d_out, int out_size, void* d_ws, size_t ws_size,
                              hipStream_t stream) {
    const float* x          = (const float*)d_in[0];
    const int*   ei         = (const int*)  d_in[1];
    const int*   batch      = (const int*)  d_in[2];
    const float* node_attr  = (const float*)d_in[3];
    const float* edge_attr  = (const float*)d_in[4];
    const float* glob_attr  = (const float*)d_in[5];
    const float* enc_node_W = (const float*)d_in[6];
    const float* enc_node_b = (const float*)d_in[7];
    const float* enc_edge_W = (const float*)d_in[8];
    const float* enc_edge_b = (const float*)d_in[9];
    const float* enc_glob_W = (const float*)d_in[10];
    const float* enc_glob_b = (const float*)d_in[11];
    const float* enc2_W     = (const float*)d_in[12];
    const float* enc2_b     = (const float*)d_in[13];
    const float* dW1 = (const float*)d_in[14]; const float* db1 = (const float*)d_in[15];
    const float* dW2 = (const float*)d_in[16]; const float* db2 = (const float*)d_in[17];
    const float* hW1 = (const float*)d_in[18]; const float* hb1 = (const float*)d_in[19];
    const float* hW2 = (const float*)d_in[20]; const float* hb2 = (const float*)d_in[21];
    const float* jW1 = (const float*)d_in[22]; const float* jb1 = (const float*)d_in[23];
    const float* jW2 = (const float*)d_in[24]; const float* jb2 = (const float*)d_in[25];
    const float* sW1 = (const float*)d_in[26]; const float* sb1 = (const float*)d_in[27];
    const float* sW2 = (const float*)d_in[28]; const float* sb2 = (const float*)d_in[29];
    const float* nW1 = (const float*)d_in[30]; const float* nb1 = (const float*)d_in[31];
    const float* nW2 = (const float*)d_in[32]; const float* nb2 = (const float*)d_in[33];
    const float* decW = (const float*)d_in[34]; const float* decb = (const float*)d_in[35];

    float* ws = (float*)d_ws;
    int4*   rs    = (int4*)ws;                           // 3.2M fl
    int4*   cs    = (int4*)(ws + 3200000);               // 3.2M fl
    __half* u_h   = (__half*)(ws + 6400000);             // 3.2M fl (-> tp_h)
    __half* v_h   = (__half*)(ws + 9600000);             // 3.2M fl (-> tm_h)
    float*  hjp   = ws + 12800000;                       // 3.2M (-> hess)
    float*  hjm   = ws + 16000000;                       // 3.2M
    float*  jac1  = ws + 19200000;                       // 3.2M (-> jac)
    float*  jac2  = ws + 22400000;                       // 3.2M
    float*  sumsp = ws + 25600000;                       // 100K
    int*    row_cnt = (int*)(ws + 25700000);             // 50176
    int*    col_cnt = row_cnt + 50176;                   // 50176
    int*    row_hd  = col_cnt + 50176;                   // 50048
    int*    col_hd  = row_hd + 50048;                    // 50048
    int*    lbr     = col_hd + 50048;                    // 7694
    int*    lbc     = lbr + 7694;                        // 7694

    // packed weights in d_out head (40,960 floats <= out_size 100,000)
    float* scratch = (float*)d_out;
    float4* puv   = (float4*)(scratch);                  // 16384 f
    float4* ptp   = (float4*)(scratch + 16384);          // 8192 f
    uint2*  pe1w1 = (uint2*)(scratch + 24576);           // 4096 f
    uint2*  pe1w2 = (uint2*)(scratch + 28672);           // 4096 f
    uint2*  pe2w1 = (uint2*)(scratch + 32768);           // 4096 f
    uint2*  pe2w2 = (uint2*)(scratch + 36864);           // 4096 f

    hipMemsetAsync(hjp, 0, (size_t)12800000*sizeof(float), stream);
    hipMemsetAsync(row_cnt, 0, (size_t)(2*50176)*sizeof(int), stream);

    k_pack_uv<<<16, 256, 0, stream>>>(dW1, puv);
    k_pack_w1<<<8, 256, 0, stream>>>(hW1, 64, ptp);
    k_pack_w1h<<<8, 256, 0, stream>>>(dW1, 128, pe1w1);
    k_pack_w2h<<<8, 256, 0, stream>>>(dW2, pe1w2);
    k_pack_w1h<<<8, 256, 0, stream>>>(hW1, 0, pe2w1);
    k_pack_w2h<<<8, 256, 0, stream>>>(hW2, pe2w2);

    // u,v (fp16) from fused node-enc + GEMM
    k_uvh<<<1563, 256, 2048*4, stream>>>(x, enc_node_W, enc_node_b, puv, u_h, v_h);

    // sorted edge records + node-aligned wave partition
    k_hist<<<3125, 256, 0, stream>>>(ei, row_cnt, col_cnt);
    k_scan<<<2, 1024, 0, stream>>>(row_cnt, row_hd, col_cnt, col_hd);
    k_scatter2<<<3125, 256, 0, stream>>>(ei, edge_attr, row_hd, col_hd, rs, cs);
    k_sumsp2<<<196, 256, 0, stream>>>(rs, row_hd, row_cnt, cs, col_hd, col_cnt, sumsp);
    k_part<<<61, 256, 0, stream>>>(row_hd, row_cnt, lbr, col_hd, col_cnt, lbc);

    const int E_BLOCKS = (NWAVES + 3) / 4;               // 1924

    // pass 1: one-sided twins, plain stores, LDS-free
    k_e1<<<E_BLOCKS, 256, 0, stream>>>(rs, u_h, v_h, lbr, row_hd, row_cnt,
                                       enc2_W, enc2_b, pe1w1, db1, pe1w2, db2, hjp);
    k_e1<<<E_BLOCKS, 256, 0, stream>>>(cs, v_h, u_h, lbc, col_hd, col_cnt,
                                       enc2_W, enc2_b, pe1w1, db1, pe1w2, db2, hjm);

    // tp,tm (fp16) overwrite u_h,v_h
    k_tptmh<<<1536, 256, 2048*4, stream>>>(hjp, hjm, ptp, u_h, v_h);

    // pass 2: col-sorted -> jac1 (tp), row-sorted -> jac2 (tm), plain stores, LDS-free
    k_e2<<<E_BLOCKS, 256, 0, stream>>>(cs, u_h, lbc, col_hd, col_cnt,
                                       enc_edge_W, enc_edge_b,
                                       pe2w1, hb1, pe2w2, hb2, jac1);
    k_e2<<<E_BLOCKS, 256, 0, stream>>>(rs, v_h, lbr, row_hd, row_cnt,
                                       enc_edge_W, enc_edge_b,
                                       pe2w1, hb1, pe2w2, hb2, jac2);

    size_t lds_nm = (4*768 + 4*512) * sizeof(float);
    k_node_mlp<<<1024, 256, lds_nm, stream>>>(jac1, jac2, sumsp, enc2_W, enc2_b,
                                              jW1, jb1, jW2, jb2, jac1);
    k_node_mlp<<<1024, 256, lds_nm, stream>>>(hjp, hjm, sumsp, enc2_W, enc2_b,
                                              sW1, sb1, sW2, sb2, hjp);

    size_t lds_nf = (4*1024 + 4*512) * sizeof(float);
    k_node_final<<<1024, 256, lds_nf, stream>>>(x, enc_node_W, enc_node_b,
                                                jac1, hjp,
                                                batch, glob_attr, enc_glob_W, enc_glob_b,
                                                nW1, nb1, nW2, nb2, decW, decb,
                                                node_attr, (float*)d_out);
}

// Round 10
// 2408.900 us; speedup vs baseline: 1.2676x; 1.2676x over previous
//
#include <hip/hip_runtime.h>
#include <hip/hip_fp16.h>
#include <math.h>

#define BN 50000
#define BE 800000
#define CHUNK 104              // target edges per wave
#define NWAVES 7693            // ceil(BE/CHUNK)

typedef _Float16 h2 __attribute__((ext_vector_type(2)));
typedef _Float16 h4 __attribute__((ext_vector_type(4)));
typedef float    f4 __attribute__((ext_vector_type(4)));

__device__ __forceinline__ float relu_f(float v) { return fmaxf(v, 0.0f); }
__device__ __forceinline__ float inv_clean(float s) {
    float q = 1.0f / s;
    return isfinite(q) ? q : 0.0f;
}
__device__ __forceinline__ float inv_clean_fast(float s) {
    float q = __builtin_amdgcn_rcpf(s);
    return isfinite(q) ? q : 0.0f;
}
__device__ __forceinline__ unsigned int h2u(h2 v) { union { h2 h; unsigned int u; } x; x.h = v; return x.u; }
__device__ __forceinline__ h2 uh2(unsigned int v) { union { unsigned int u; h2 h; } x; x.u = v; return x.h; }
__device__ __forceinline__ unsigned int packh2(float a, float b) {
    h2 h; h.x = (_Float16)a; h.y = (_Float16)b; return h2u(h);
}
__device__ __forceinline__ h4 u2h4(uint2 v) { union { uint2 u; h4 h; } x; x.u = v; return x.h; }

// ===========================================================================
// Weight packing (outputs in d_out head; k_node_final overwrites d_out last)
// ===========================================================================
// fp32 pair-pack rows r0..r0+63 of [*,128] (for k_tptmh)
__global__ __launch_bounds__(256) void k_pack_w1(
    const float* __restrict__ W, int r0, float4* __restrict__ dst)
{
    int t = blockIdx.x * 256 + threadIdx.x;
    if (t >= 2048) return;
    int j2 = t >> 6, l = t & 63;
    const float* ra = W + (size_t)(r0 + 2*j2) * 128 + 2*l;
    const float* rb = W + (size_t)(r0 + 2*j2 + 1) * 128 + 2*l;
    dst[t] = make_float4(ra[0], ra[1], rb[0], rb[1]);
}
// fp32 pack dW1 rows 0..127 for k_uvh
__global__ __launch_bounds__(256) void k_pack_uv(
    const float* __restrict__ dW1, float4* __restrict__ dst)
{
    int t = blockIdx.x * 256 + threadIdx.x;
    if (t >= 4096) return;
    int j = t >> 6, l = t & 63;
    float4 w;
    if (l < 32) w = ((const float4*)(dW1 + (size_t)j*128))[l];
    else        w = ((const float4*)(dW1 + (size_t)(64+j)*128))[l-32];
    dst[t] = w;
}
// MFMA A-fragment pack, layer-1: frag (n,s): A[i][k] = W[r0 + s*16 + k][n*16 + i]
// lane l: i = l&15, k = (l>>4)*4 + r  (v_mfma_f32_16x16x16_f16 A layout)
__global__ __launch_bounds__(256) void k_pack_a1(
    const float* __restrict__ W, int r0, uint2* __restrict__ dst)
{
    int t = blockIdx.x * 256 + threadIdx.x;   // 2048 total (32 frags x 64 lanes)
    if (t >= 2048) return;
    int frag = t >> 6, l = t & 63;
    int n = frag >> 2, s = frag & 3;
    int i = l & 15, kq = l >> 4;
    size_t base = (size_t)(r0 + s*16 + kq*4) * 128 + n*16 + i;
    float w0 = W[base + 0*128];
    float w1 = W[base + 1*128];
    float w2 = W[base + 2*128];
    float w3 = W[base + 3*128];
    dst[t] = make_uint2(packh2(w0, w1), packh2(w2, w3));
}
// MFMA A-fragment pack, layer-2: frag (m,n): A[i][k] = W2[n*16 + k][m*16 + i]
__global__ __launch_bounds__(256) void k_pack_a2(
    const float* __restrict__ W2, uint2* __restrict__ dst)
{
    int t = blockIdx.x * 256 + threadIdx.x;   // 2048 total
    if (t >= 2048) return;
    int frag = t >> 6, l = t & 63;
    int m = frag >> 3, n = frag & 7;
    int i = l & 15, kq = l >> 4;
    size_t base = (size_t)(n*16 + kq*4) * 64 + m*16 + i;
    float w0 = W2[base + 0*64];
    float w1 = W2[base + 1*64];
    float w2 = W2[base + 2*64];
    float w3 = W2[base + 3*64];
    dst[t] = make_uint2(packh2(w0, w1), packh2(w2, w3));
}

// ===========================================================================
// CSR-ish build
// ===========================================================================
__global__ __launch_bounds__(256) void k_hist(
    const int* __restrict__ ei, int* __restrict__ rc, int* __restrict__ cc)
{
    int e = blockIdx.x * 256 + threadIdx.x;
    if (e >= BE) return;
    atomicAdd(&rc[ei[e]], 1);
    atomicAdd(&cc[ei[BE + e]], 1);
}

__global__ __launch_bounds__(1024) void k_scan(
    const int* __restrict__ cntR, int* __restrict__ hdR,
    const int* __restrict__ cntC, int* __restrict__ hdC)
{
    __shared__ int s[1024];
    const int* cnt; int* hd;
    if (blockIdx.x == 0) { cnt = cntR; hd = hdR; }
    else                 { cnt = cntC; hd = hdC; }
    int t = threadIdx.x;
    int base = t * 49;
    int sum = 0;
    for (int i = 0; i < 49; i++) {
        int idx = base + i;
        sum += (idx < BN) ? cnt[idx] : 0;
    }
    s[t] = sum;
    __syncthreads();
    for (int o = 1; o < 1024; o <<= 1) {
        int v = (t >= o) ? s[t - o] : 0;
        __syncthreads();
        s[t] += v;
        __syncthreads();
    }
    int run = s[t] - sum;
    for (int i = 0; i < 49; i++) {
        int idx = base + i;
        if (idx < BN) { hd[idx] = run; run += cnt[idx]; }
    }
}

__global__ __launch_bounds__(256) void k_scatter2(
    const int* __restrict__ ei, const float* __restrict__ ea,
    int* __restrict__ rhd, int* __restrict__ chd,
    int4* __restrict__ rs, int4* __restrict__ cs)
{
    int e = blockIdx.x * 256 + threadIdx.x;
    if (e >= BE) return;
    int r = ei[e], c = ei[BE + e];
    float2 s = ((const float2*)ea)[e];
    int s0 = __float_as_int(s.x), s1 = __float_as_int(s.y);
    int p1 = atomicAdd(&rhd[r], 1);
    rs[p1] = make_int4(r, c, s0, s1);
    int p2 = atomicAdd(&chd[c], 1);
    cs[p2] = make_int4(c, r, s0, s1);
}

// sumsp from sorted records (hd = end offsets after scatter)
__global__ __launch_bounds__(256) void k_sumsp2(
    const int4* __restrict__ rs, const int* __restrict__ rhd, const int* __restrict__ rcnt,
    const int4* __restrict__ cs, const int* __restrict__ chd, const int* __restrict__ ccnt,
    float* __restrict__ sumsp)
{
    int n = blockIdx.x * 256 + threadIdx.x;
    if (n >= BN) return;
    float s0 = 0.f, s1 = 0.f;
    int e1 = rhd[n], e0 = e1 - rcnt[n];
    for (int j = e0; j < e1; j++) {
        int4 rec = rs[j];
        s0 += __int_as_float(rec.z); s1 += __int_as_float(rec.w);
    }
    e1 = chd[n]; e0 = e1 - ccnt[n];
    for (int j = e0; j < e1; j++) {
        int4 rec = cs[j];
        s0 += __int_as_float(rec.z); s1 += __int_as_float(rec.w);
    }
    sumsp[2*n]   = s0;
    sumsp[2*n+1] = s1;
}

// Node-aligned wave partition: lb[w] = first node whose start offset >= w*CHUNK.
__global__ __launch_bounds__(256) void k_part(
    const int* __restrict__ rhd, const int* __restrict__ rcnt, int* __restrict__ lbr,
    const int* __restrict__ chd, const int* __restrict__ ccnt, int* __restrict__ lbc)
{
    int t = blockIdx.x * 256 + threadIdx.x;
    if (t >= 2 * (NWAVES + 1)) return;
    int which = (t > NWAVES) ? 1 : 0;
    int w = t - which * (NWAVES + 1);
    const int* hd  = which ? chd  : rhd;
    const int* cnt = which ? ccnt : rcnt;
    int* lb        = which ? lbc  : lbr;
    if (w == NWAVES) { lb[NWAVES] = BN; return; }
    int target = w * CHUNK;
    int lo = 0, hi = BN;
    while (lo < hi) {
        int mid = (lo + hi) >> 1;
        int s = hd[mid] - cnt[mid];       // start offset of node mid
        if (s >= target) hi = mid; else lo = mid + 1;
    }
    lb[w] = lo;
}

// ===========================================================================
// k_uvh: fused node-enc + uv GEMM; outputs u,v in fp16
// ===========================================================================
__global__ __launch_bounds__(256, 6) void k_uvh(
    const float* __restrict__ x,
    const float* __restrict__ enW, const float* __restrict__ enB,
    const float4* __restrict__ guv,
    __half* __restrict__ u_h, __half* __restrict__ v_h)
{
    extern __shared__ float lds[];
    const int wid = threadIdx.x >> 6, l = threadIdx.x & 63;
    float4* xb4 = (float4*)(lds + wid * 512);
    const int gw = blockIdx.x * 4 + wid;
    const int nw = gridDim.x * 4;

    const int jj = l & 31;
    const float w0a = enW[jj],    w0b = enW[64+jj],  b0 = enB[jj];
    const float w1a = enW[jj+32], w1b = enW[96+jj],  b1 = enB[jj+32];

    for (int g = gw; g < BN/8; g += nw) {
        const int n0 = g * 8;
        const int q = l >> 5;
        {
            float2 xa = ((const float2*)x)[n0 + q*4 + 0];
            float2 xb = ((const float2*)x)[n0 + q*4 + 1];
            float2 xc = ((const float2*)x)[n0 + q*4 + 2];
            float2 xd = ((const float2*)x)[n0 + q*4 + 3];
            float4 p0, p1;
            p0.x = relu_f(fmaf(xa.x, w0a, fmaf(xa.y, w0b, b0)));
            p0.y = relu_f(fmaf(xb.x, w0a, fmaf(xb.y, w0b, b0)));
            p0.z = relu_f(fmaf(xc.x, w0a, fmaf(xc.y, w0b, b0)));
            p0.w = relu_f(fmaf(xd.x, w0a, fmaf(xd.y, w0b, b0)));
            p1.x = relu_f(fmaf(xa.x, w1a, fmaf(xa.y, w1b, b1)));
            p1.y = relu_f(fmaf(xb.x, w1a, fmaf(xb.y, w1b, b1)));
            p1.z = relu_f(fmaf(xc.x, w1a, fmaf(xc.y, w1b, b1)));
            p1.w = relu_f(fmaf(xd.x, w1a, fmaf(xd.y, w1b, b1)));
            xb4[jj*2 + q]      = p0;
            xb4[(jj+32)*2 + q] = p1;
        }
        float4 acc[8];
        #pragma unroll
        for (int e = 0; e < 8; e++) acc[e] = make_float4(0,0,0,0);
        #pragma unroll 8
        for (int j = 0; j < 64; j++) {
            float4 wq = guv[j*64 + l];
            float4 xa = xb4[j*2 + 0];
            float4 xc = xb4[j*2 + 1];
            acc[0].x = fmaf(xa.x, wq.x, acc[0].x); acc[0].y = fmaf(xa.x, wq.y, acc[0].y);
            acc[0].z = fmaf(xa.x, wq.z, acc[0].z); acc[0].w = fmaf(xa.x, wq.w, acc[0].w);
            acc[1].x = fmaf(xa.y, wq.x, acc[1].x); acc[1].y = fmaf(xa.y, wq.y, acc[1].y);
            acc[1].z = fmaf(xa.y, wq.z, acc[1].z); acc[1].w = fmaf(xa.y, wq.w, acc[1].w);
            acc[2].x = fmaf(xa.z, wq.x, acc[2].x); acc[2].y = fmaf(xa.z, wq.y, acc[2].y);
            acc[2].z = fmaf(xa.z, wq.z, acc[2].z); acc[2].w = fmaf(xa.z, wq.w, acc[2].w);
            acc[3].x = fmaf(xa.w, wq.x, acc[3].x); acc[3].y = fmaf(xa.w, wq.y, acc[3].y);
            acc[3].z = fmaf(xa.w, wq.z, acc[3].z); acc[3].w = fmaf(xa.w, wq.w, acc[3].w);
            acc[4].x = fmaf(xc.x, wq.x, acc[4].x); acc[4].y = fmaf(xc.x, wq.y, acc[4].y);
            acc[4].z = fmaf(xc.x, wq.z, acc[4].z); acc[4].w = fmaf(xc.x, wq.w, acc[4].w);
            acc[5].x = fmaf(xc.y, wq.x, acc[5].x); acc[5].y = fmaf(xc.y, wq.y, acc[5].y);
            acc[5].z = fmaf(xc.y, wq.z, acc[5].z); acc[5].w = fmaf(xc.y, wq.w, acc[5].w);
            acc[6].x = fmaf(xc.z, wq.x, acc[6].x); acc[6].y = fmaf(xc.z, wq.y, acc[6].y);
            acc[6].z = fmaf(xc.z, wq.z, acc[6].z); acc[6].w = fmaf(xc.z, wq.w, acc[6].w);
            acc[7].x = fmaf(xc.w, wq.x, acc[7].x); acc[7].y = fmaf(xc.w, wq.y, acc[7].y);
            acc[7].z = fmaf(xc.w, wq.z, acc[7].z); acc[7].w = fmaf(xc.w, wq.w, acc[7].w);
        }
        __half* dst = (l < 32) ? (u_h + 4*l) : (v_h + 4*(l-32));
        #pragma unroll
        for (int e = 0; e < 8; e++) {
            __half2* p = (__half2*)(dst + (size_t)(n0+e)*128);
            p[0] = __floats2half2_rn(acc[e].x, acc[e].y);
            p[1] = __floats2half2_rn(acc[e].z, acc[e].w);
        }
    }
}

// ===========================================================================
// k_em<MODE>: MFMA edge kernel. 16 edges per wave-batch, v_mfma_f32_16x16x16_f16.
//   MODE 0 (pass 1): x = relu(enc2(1/sp)); t = W1c*x + u[key] + v[oth] + b1
//   MODE 1 (pass 2): x = relu(enc_edge(sp)); t = W1a*x + tvals[key] + b1
//   o = W2*relu(t) + b2; run-merged plain stores into out[key].
// Layer-1 D-frag (lane: edge=l&15, ch=(l>>4)*4+r) IS layer-2's B-frag: no shuffle.
// Epilogue: wave-private LDS transpose [16][68] then in-lane run merge.
// ===========================================================================
template<int MODE>
__global__ __launch_bounds__(256, 4) void k_em(
    const int4* __restrict__ recs,
    const __half* __restrict__ A_h, const __half* __restrict__ B_h,
    const int* __restrict__ lb, const int* __restrict__ hd, const int* __restrict__ cnt,
    const float* __restrict__ ew, const float* __restrict__ ebv,
    const uint2* __restrict__ pa1, const float* __restrict__ b1g,
    const uint2* __restrict__ pa2, const float* __restrict__ b2g,
    float* __restrict__ out)
{
    extern __shared__ float lds[];
    const int l = threadIdx.x & 63, wid = threadIdx.x >> 6;
    float* sbuf = lds + wid * (16 * 68);

    const int wave = blockIdx.x * 4 + wid;
    if (wave >= NWAVES) return;
    const int nlo = lb[wave], nhi = lb[wave + 1];
    if (nlo >= nhi) return;
    const int eb = hd[nlo] - cnt[nlo];
    const int ee = (nhi < BN) ? (hd[nhi] - cnt[nhi]) : BE;
    if (eb >= ee) return;

    const int kq = l >> 4, li = l & 15;
    const float b2r = b2g[l];

    float acc = 0.f;
    int cur = -1;

    for (int i0 = eb; i0 < ee; i0 += 16) {
        const int nact = min(16, ee - i0);
        int4 rec = recs[i0 + min(li, nact - 1)];
        const int mykey = rec.x, myoth = rec.y;
        float q0 = __int_as_float(rec.z), q1 = __int_as_float(rec.w);
        if (MODE == 0) { q0 = inv_clean_fast(q0); q1 = inv_clean_fast(q1); }

        // B1 fragments: x[ch = s*16 + kq*4 + r] of my edge (li)
        h4 xb[4];
        #pragma unroll
        for (int s = 0; s < 4; s++) {
            const float4 wA = *(const float4*)(ew + s*16 + kq*4);
            const float4 wB = *(const float4*)(ew + 64 + s*16 + kq*4);
            const float4 bb = *(const float4*)(ebv + s*16 + kq*4);
            h4 xv;
            xv[0] = (_Float16)relu_f(fmaf(q0, wA.x, fmaf(q1, wB.x, bb.x)));
            xv[1] = (_Float16)relu_f(fmaf(q0, wA.y, fmaf(q1, wB.y, bb.y)));
            xv[2] = (_Float16)relu_f(fmaf(q0, wA.z, fmaf(q1, wB.z, bb.z)));
            xv[3] = (_Float16)relu_f(fmaf(q0, wA.w, fmaf(q1, wB.w, bb.w)));
            xb[s] = xv;
        }

        // Layer-1 MFMA (8 ch-tiles x 4 k-steps) fused into h fragments
        h4 hf[8];
        #pragma unroll
        for (int n = 0; n < 8; n++) {
            f4 a1 = {0.f, 0.f, 0.f, 0.f};
            #pragma unroll
            for (int s = 0; s < 4; s++)
                a1 = __builtin_amdgcn_mfma_f32_16x16x16f16(
                        u2h4(pa1[(n*4 + s)*64 + l]), xb[s], a1, 0, 0, 0);
            const float4 b1q = *(const float4*)(b1g + n*16 + kq*4);
            float t0, t1, t2, t3;
            if (MODE == 0) {
                uint2 uu = *(const uint2*)(A_h + (size_t)mykey*128 + n*16 + kq*4);
                uint2 vv = *(const uint2*)(B_h + (size_t)myoth*128 + n*16 + kq*4);
                h2 ul = uh2(uu.x), uhh = uh2(uu.y), vl = uh2(vv.x), vhh = uh2(vv.y);
                t0 = a1[0] + b1q.x + (float)ul.x  + (float)vl.x;
                t1 = a1[1] + b1q.y + (float)ul.y  + (float)vl.y;
                t2 = a1[2] + b1q.z + (float)uhh.x + (float)vhh.x;
                t3 = a1[3] + b1q.w + (float)uhh.y + (float)vhh.y;
            } else {
                uint2 tt = *(const uint2*)(A_h + (size_t)mykey*128 + n*16 + kq*4);
                h2 tl = uh2(tt.x), th = uh2(tt.y);
                t0 = a1[0] + b1q.x + (float)tl.x;
                t1 = a1[1] + b1q.y + (float)tl.y;
                t2 = a1[2] + b1q.z + (float)th.x;
                t3 = a1[3] + b1q.w + (float)th.y;
            }
            h4 hv;
            hv[0] = (_Float16)relu_f(t0);
            hv[1] = (_Float16)relu_f(t1);
            hv[2] = (_Float16)relu_f(t2);
            hv[3] = (_Float16)relu_f(t3);
            hf[n] = hv;
        }

        // Layer-2 MFMA (4 out-tiles x 8 k-steps); D: edge=l&15, outch=(l>>4)*4+r+m*16
        #pragma unroll
        for (int m = 0; m < 4; m++) {
            f4 a2 = {0.f, 0.f, 0.f, 0.f};
            #pragma unroll
            for (int n = 0; n < 8; n++)
                a2 = __builtin_amdgcn_mfma_f32_16x16x16f16(
                        u2h4(pa2[(m*8 + n)*64 + l]), hf[n], a2, 0, 0, 0);
            *(float4*)(sbuf + li*68 + m*16 + kq*4) =
                make_float4(a2[0], a2[1], a2[2], a2[3]);
        }

        // merge epilogue: lane = outch l, serial over edges (keys via readlane)
        #pragma unroll
        for (int e = 0; e < 16; e++) {
            if (e < nact) {
                int ke = __builtin_amdgcn_readlane(mykey, e);
                float val = sbuf[e*68 + l] + b2r;
                if (ke != cur) {
                    if (cur >= 0) out[(size_t)cur*64 + l] = acc;   // plain store
                    acc = 0.f;
                    cur = ke;
                }
                acc += val;
            }
        }
    }
    if (cur >= 0) out[(size_t)cur*64 + l] = acc;
}

// ===========================================================================
// k_tptmh: tp[n] = hjp[n] @ hW1[64:128,:], tm[n] = hjm[n] @ hW1[64:128,:]  (fp16 out)
// ===========================================================================
__global__ __launch_bounds__(256, 6) void k_tptmh(
    const float* __restrict__ hjp, const float* __restrict__ hjm,
    const float4* __restrict__ gtp,
    __half* __restrict__ tp_h, __half* __restrict__ tm_h)
{
    extern __shared__ float lds[];
    const int wid = threadIdx.x >> 6, l = threadIdx.x & 63;
    float4* xb4 = (float4*)(lds + wid * 512);
    const int gw = blockIdx.x * 4 + wid;
    const int nw = gridDim.x * 4;
    const int NG = BN/8;

    for (int vg = gw; vg < 2*NG; vg += nw) {
        const float* in = (vg < NG) ? hjp : hjm;
        __half*     out = (vg < NG) ? tp_h : tm_h;
        const int n0 = ((vg < NG) ? vg : vg - NG) * 8;
        const int q = l >> 5;
        #pragma unroll
        for (int r = 0; r < 2; r++) {
            int j = (l & 31) + 32*r;
            float v0 = in[(n0 + q*4 + 0)*64 + j];
            float v1 = in[(n0 + q*4 + 1)*64 + j];
            float v2 = in[(n0 + q*4 + 2)*64 + j];
            float v3 = in[(n0 + q*4 + 3)*64 + j];
            xb4[j*2 + q] = make_float4(v0, v1, v2, v3);
        }
        float a0[8] = {0,0,0,0,0,0,0,0}, a1[8] = {0,0,0,0,0,0,0,0};
        #pragma unroll 8
        for (int j2 = 0; j2 < 32; j2++) {
            float4 wq = gtp[j2*64 + l];
            float4 xa = xb4[(2*j2)*2 + 0];
            float4 xbv = xb4[(2*j2)*2 + 1];
            float4 xc = xb4[(2*j2+1)*2 + 0];
            float4 xd = xb4[(2*j2+1)*2 + 1];
            a0[0] = fmaf(xa.x, wq.x, fmaf(xc.x, wq.z, a0[0]));
            a1[0] = fmaf(xa.x, wq.y, fmaf(xc.x, wq.w, a1[0]));
            a0[1] = fmaf(xa.y, wq.x, fmaf(xc.y, wq.z, a0[1]));
            a1[1] = fmaf(xa.y, wq.y, fmaf(xc.y, wq.w, a1[1]));
            a0[2] = fmaf(xa.z, wq.x, fmaf(xc.z, wq.z, a0[2]));
            a1[2] = fmaf(xa.z, wq.y, fmaf(xc.z, wq.w, a1[2]));
            a0[3] = fmaf(xa.w, wq.x, fmaf(xc.w, wq.z, a0[3]));
            a1[3] = fmaf(xa.w, wq.y, fmaf(xc.w, wq.w, a1[3]));
            a0[4] = fmaf(xbv.x, wq.x, fmaf(xd.x, wq.z, a0[4]));
            a1[4] = fmaf(xbv.x, wq.y, fmaf(xd.x, wq.w, a1[4]));
            a0[5] = fmaf(xbv.y, wq.x, fmaf(xd.y, wq.z, a0[5]));
            a1[5] = fmaf(xbv.y, wq.y, fmaf(xd.y, wq.w, a1[5]));
            a0[6] = fmaf(xbv.z, wq.x, fmaf(xd.z, wq.z, a0[6]));
            a1[6] = fmaf(xbv.z, wq.y, fmaf(xd.z, wq.w, a1[6]));
            a0[7] = fmaf(xbv.w, wq.x, fmaf(xd.w, wq.z, a0[7]));
            a1[7] = fmaf(xbv.w, wq.y, fmaf(xd.w, wq.w, a1[7]));
        }
        #pragma unroll
        for (int e = 0; e < 8; e++) {
            *(__half2*)(out + (size_t)(n0+e)*128 + 2*l) = __floats2half2_rn(a0[e], a1[e]);
        }
    }
}

// ===========================================================================
// Node MLP kernels (fp32, weights streamed from global)
// ===========================================================================
__global__ __launch_bounds__(256, 4) void k_node_mlp(
    const float* __restrict__ A, const float* __restrict__ Bv,
    const float* __restrict__ sumsp,
    const float* __restrict__ e2w_g, const float* __restrict__ e2b_g,
    const float* __restrict__ W1g, const float* __restrict__ b1g,
    const float* __restrict__ W2g, const float* __restrict__ b2g,
    float* __restrict__ outp)
{
    extern __shared__ float lds[];
    const int wid = threadIdx.x >> 6, l = threadIdx.x & 63;
    float* xbuf = lds + wid * 768;
    float* hbuf = lds + 4*768 + wid * 512;

    const float ewl = e2w_g[l], ewl2 = e2w_g[64+l], ebl = e2b_g[l];
    const float bb0 = b1g[2*l], bb1 = b1g[2*l+1];
    const float bo = b2g[l];

    const int gw = blockIdx.x * 4 + wid;
    const int nw = gridDim.x * 4;

    for (int g = gw; g < BN/4; g += nw) {
        const int i0 = g * 4;
        float av[4], bv[4], iv[4];
        #pragma unroll
        for (int e = 0; e < 4; e++) {
            int i = i0 + e;
            av[e] = A[i*64 + l];
            bv[e] = Bv[i*64 + l];
            float q0 = inv_clean(sumsp[i*2+0]);
            float q1 = inv_clean(sumsp[i*2+1]);
            iv[e] = relu_f(fmaf(q0, ewl, fmaf(q1, ewl2, ebl)));
        }
        ((float4*)xbuf)[l]       = make_float4(av[0], av[1], av[2], av[3]);
        ((float4*)xbuf)[64 + l]  = make_float4(bv[0], bv[1], bv[2], bv[3]);
        ((float4*)xbuf)[128 + l] = make_float4(iv[0], iv[1], iv[2], iv[3]);

        float acc0[4] = {0,0,0,0}, acc1[4] = {0,0,0,0};
        #pragma unroll 8
        for (int j = 0; j < 192; j++) {
            float4 xv = ((const float4*)xbuf)[j];
            float2 wv = ((const float2*)(W1g + j*128))[l];
            acc0[0] = fmaf(xv.x, wv.x, acc0[0]);
            acc0[1] = fmaf(xv.y, wv.x, acc0[1]);
            acc0[2] = fmaf(xv.z, wv.x, acc0[2]);
            acc0[3] = fmaf(xv.w, wv.x, acc0[3]);
            acc1[0] = fmaf(xv.x, wv.y, acc1[0]);
            acc1[1] = fmaf(xv.y, wv.y, acc1[1]);
            acc1[2] = fmaf(xv.z, wv.y, acc1[2]);
            acc1[3] = fmaf(xv.w, wv.y, acc1[3]);
        }
        #pragma unroll
        for (int e = 0; e < 4; e++) {
            ((float2*)(hbuf + e*128))[l] = make_float2(relu_f(acc0[e]+bb0), relu_f(acc1[e]+bb1));
        }
        float o[4] = {0,0,0,0};
        #pragma unroll 8
        for (int k = 0; k < 128; k++) {
            float wv = W2g[k*64 + l];
            o[0] = fmaf(hbuf[0*128+k], wv, o[0]);
            o[1] = fmaf(hbuf[1*128+k], wv, o[1]);
            o[2] = fmaf(hbuf[2*128+k], wv, o[2]);
            o[3] = fmaf(hbuf[3*128+k], wv, o[3]);
        }
        #pragma unroll
        for (int e = 0; e < 4; e++) outp[(i0+e)*64 + l] = o[e] + bo;
    }
}

__global__ __launch_bounds__(256, 4) void k_node_final(
    const float* __restrict__ x,
    const float* __restrict__ enW, const float* __restrict__ enB,
    const float* __restrict__ jacv, const float* __restrict__ hessv,
    const int* __restrict__ batch, const float* __restrict__ ga,
    const float* __restrict__ gw_g, const float* __restrict__ gb_g,
    const float* __restrict__ nW1, const float* __restrict__ nb1,
    const float* __restrict__ nW2, const float* __restrict__ nb2,
    const float* __restrict__ decW, const float* __restrict__ decb,
    const float* __restrict__ node_attr, float* __restrict__ outp)
{
    extern __shared__ float lds[];
    const int wid = threadIdx.x >> 6, l = threadIdx.x & 63;
    float* xbuf = lds + wid * 1024;
    float* hbuf = lds + 4*1024 + wid * 512;

    const float gwl = gw_g[l], gwl2 = gw_g[64+l], gbl = gb_g[l];
    const float enw0 = enW[l], enw1 = enW[64+l], enb = enB[l];
    const float bb0 = nb1[2*l], bb1 = nb1[2*l+1];
    const float bo = nb2[l];

    const int gwv = blockIdx.x * 4 + wid;
    const int nw = gridDim.x * 4;

    for (int g = gwv; g < BN/4; g += nw) {
        const int i0 = g * 4;
        float ne[4], jv[4], ge[4], hv[4];
        #pragma unroll
        for (int e = 0; e < 4; e++) {
            int i = i0 + e;
            ne[e] = relu_f(fmaf(x[i*2], enw0, fmaf(x[i*2+1], enw1, enb)));
            jv[e] = jacv[i*64 + l];
            hv[e] = hessv[i*64 + l];
            int gi = batch[i];
            ge[e] = relu_f(fmaf(ga[gi*2], gwl, fmaf(ga[gi*2+1], gwl2, gbl)));
        }
        ((float4*)xbuf)[l]       = make_float4(ne[0], ne[1], ne[2], ne[3]);
        ((float4*)xbuf)[64 + l]  = make_float4(jv[0], jv[1], jv[2], jv[3]);
        ((float4*)xbuf)[128 + l] = make_float4(ge[0], ge[1], ge[2], ge[3]);
        ((float4*)xbuf)[192 + l] = make_float4(hv[0], hv[1], hv[2], hv[3]);

        float acc0[4] = {0,0,0,0}, acc1[4] = {0,0,0,0};
        #pragma unroll 8
        for (int j = 0; j < 256; j++) {
            float4 xv = ((const float4*)xbuf)[j];
            float2 wv = ((const float2*)(nW1 + j*128))[l];
            acc0[0] = fmaf(xv.x, wv.x, acc0[0]);
            acc0[1] = fmaf(xv.y, wv.x, acc0[1]);
            acc0[2] = fmaf(xv.z, wv.x, acc0[2]);
            acc0[3] = fmaf(xv.w, wv.x, acc0[3]);
            acc1[0] = fmaf(xv.x, wv.y, acc1[0]);
            acc1[1] = fmaf(xv.y, wv.y, acc1[1]);
            acc1[2] = fmaf(xv.z, wv.y, acc1[2]);
            acc1[3] = fmaf(xv.w, wv.y, acc1[3]);
        }
        #pragma unroll
        for (int e = 0; e < 4; e++) {
            ((float2*)(hbuf + e*128))[l] = make_float2(relu_f(acc0[e]+bb0), relu_f(acc1[e]+bb1));
        }
        float o[4] = {0,0,0,0};
        #pragma unroll 8
        for (int k = 0; k < 128; k++) {
            float wv = nW2[k*64 + l];
            o[0] = fmaf(hbuf[0*128+k], wv, o[0]);
            o[1] = fmaf(hbuf[1*128+k], wv, o[1]);
            o[2] = fmaf(hbuf[2*128+k], wv, o[2]);
            o[3] = fmaf(hbuf[3*128+k], wv, o[3]);
        }
        #pragma unroll
        for (int e = 0; e < 4; e++) hbuf[e*128 + l] = o[e] + bo;

        int e2 = l >> 4, sub = l & 15, j2 = sub >> 3, part = sub & 7;
        float s = 0.0f;
        #pragma unroll
        for (int kk = 0; kk < 8; kk++) {
            int k = part*8 + kk;
            s = fmaf(hbuf[e2*128 + k], decW[k*2 + j2], s);
        }
        s += __shfl_xor(s, 1);
        s += __shfl_xor(s, 2);
        s += __shfl_xor(s, 4);
        if (part == 0) {
            int i = i0 + e2;
            outp[i*2 + j2] = (s + decb[j2]) * node_attr[i*2 + j2];
        }
    }
}

// ===========================================================================
extern "C" void kernel_launch(void* const* d_in, const int* in_sizes, int n_in,
                              void* d_out, int out_size, void* d_ws, size_t ws_size,
                              hipStream_t stream) {
    const float* x          = (const float*)d_in[0];
    const int*   ei         = (const int*)  d_in[1];
    const int*   batch      = (const int*)  d_in[2];
    const float* node_attr  = (const float*)d_in[3];
    const float* edge_attr  = (const float*)d_in[4];
    const float* glob_attr  = (const float*)d_in[5];
    const float* enc_node_W = (const float*)d_in[6];
    const float* enc_node_b = (const float*)d_in[7];
    const float* enc_edge_W = (const float*)d_in[8];
    const float* enc_edge_b = (const float*)d_in[9];
    const float* enc_glob_W = (const float*)d_in[10];
    const float* enc_glob_b = (const float*)d_in[11];
    const float* enc2_W     = (const float*)d_in[12];
    const float* enc2_b     = (const float*)d_in[13];
    const float* dW1 = (const float*)d_in[14]; const float* db1 = (const float*)d_in[15];
    const float* dW2 = (const float*)d_in[16]; const float* db2 = (const float*)d_in[17];
    const float* hW1 = (const float*)d_in[18]; const float* hb1 = (const float*)d_in[19];
    const float* hW2 = (const float*)d_in[20]; const float* hb2 = (const float*)d_in[21];
    const float* jW1 = (const float*)d_in[22]; const float* jb1 = (const float*)d_in[23];
    const float* jW2 = (const float*)d_in[24]; const float* jb2 = (const float*)d_in[25];
    const float* sW1 = (const float*)d_in[26]; const float* sb1 = (const float*)d_in[27];
    const float* sW2 = (const float*)d_in[28]; const float* sb2 = (const float*)d_in[29];
    const float* nW1 = (const float*)d_in[30]; const float* nb1 = (const float*)d_in[31];
    const float* nW2 = (const float*)d_in[32]; const float* nb2 = (const float*)d_in[33];
    const float* decW = (const float*)d_in[34]; const float* decb = (const float*)d_in[35];

    float* ws = (float*)d_ws;
    int4*   rs    = (int4*)ws;                           // 3.2M fl
    int4*   cs    = (int4*)(ws + 3200000);               // 3.2M fl
    __half* u_h   = (__half*)(ws + 6400000);             // 3.2M fl (-> tp_h)
    __half* v_h   = (__half*)(ws + 9600000);             // 3.2M fl (-> tm_h)
    float*  hjp   = ws + 12800000;                       // 3.2M (-> hess)
    float*  hjm   = ws + 16000000;                       // 3.2M
    float*  jac1  = ws + 19200000;                       // 3.2M (-> jac)
    float*  jac2  = ws + 22400000;                       // 3.2M
    float*  sumsp = ws + 25600000;                       // 100K
    int*    row_cnt = (int*)(ws + 25700000);             // 50176
    int*    col_cnt = row_cnt + 50176;                   // 50176
    int*    row_hd  = col_cnt + 50176;                   // 50048
    int*    col_hd  = row_hd + 50048;                    // 50048
    int*    lbr     = col_hd + 50048;                    // 7694
    int*    lbc     = lbr + 7694;                        // 7694

    // packed weights in d_out head (40,960 floats <= out_size 100,000)
    float* scratch = (float*)d_out;
    float4* puv   = (float4*)(scratch);                  // 16384 f
    float4* ptp   = (float4*)(scratch + 16384);          // 8192 f
    uint2*  pa1e1 = (uint2*)(scratch + 24576);           // 4096 f
    uint2*  pa2e1 = (uint2*)(scratch + 28672);           // 4096 f
    uint2*  pa1e2 = (uint2*)(scratch + 32768);           // 4096 f
    uint2*  pa2e2 = (uint2*)(scratch + 36864);           // 4096 f

    hipMemsetAsync(hjp, 0, (size_t)12800000*sizeof(float), stream);
    hipMemsetAsync(row_cnt, 0, (size_t)(2*50176)*sizeof(int), stream);

    k_pack_uv<<<16, 256, 0, stream>>>(dW1, puv);
    k_pack_w1<<<8, 256, 0, stream>>>(hW1, 64, ptp);
    k_pack_a1<<<8, 256, 0, stream>>>(dW1, 128, pa1e1);   // ise block of dW1
    k_pack_a2<<<8, 256, 0, stream>>>(dW2, pa2e1);
    k_pack_a1<<<8, 256, 0, stream>>>(hW1, 0, pa1e2);     // se block of hW1
    k_pack_a2<<<8, 256, 0, stream>>>(hW2, pa2e2);

    // u,v (fp16) from fused node-enc + GEMM
    k_uvh<<<1563, 256, 2048*4, stream>>>(x, enc_node_W, enc_node_b, puv, u_h, v_h);

    // sorted edge records + node-aligned wave partition
    k_hist<<<3125, 256, 0, stream>>>(ei, row_cnt, col_cnt);
    k_scan<<<2, 1024, 0, stream>>>(row_cnt, row_hd, col_cnt, col_hd);
    k_scatter2<<<3125, 256, 0, stream>>>(ei, edge_attr, row_hd, col_hd, rs, cs);
    k_sumsp2<<<196, 256, 0, stream>>>(rs, row_hd, row_cnt, cs, col_hd, col_cnt, sumsp);
    k_part<<<61, 256, 0, stream>>>(row_hd, row_cnt, lbr, col_hd, col_cnt, lbc);

    const int E_BLOCKS = (NWAVES + 3) / 4;               // 1924
    const size_t lds_e = 4 * 16 * 68 * sizeof(float);    // 17408 B

    // pass 1: MFMA one-sided twins, plain stores
    k_em<0><<<E_BLOCKS, 256, lds_e, stream>>>(rs, u_h, v_h, lbr, row_hd, row_cnt,
                                              enc2_W, enc2_b, pa1e1, db1, pa2e1, db2, hjp);
    k_em<0><<<E_BLOCKS, 256, lds_e, stream>>>(cs, v_h, u_h, lbc, col_hd, col_cnt,
                                              enc2_W, enc2_b, pa1e1, db1, pa2e1, db2, hjm);

    // tp,tm (fp16) overwrite u_h,v_h
    k_tptmh<<<1536, 256, 2048*4, stream>>>(hjp, hjm, ptp, u_h, v_h);

    // pass 2: col-sorted -> jac1 (tp), row-sorted -> jac2 (tm)
    k_em<1><<<E_BLOCKS, 256, lds_e, stream>>>(cs, u_h, u_h, lbc, col_hd, col_cnt,
                                              enc_edge_W, enc_edge_b, pa1e2, hb1, pa2e2, hb2, jac1);
    k_em<1><<<E_BLOCKS, 256, lds_e, stream>>>(rs, v_h, v_h, lbr, row_hd, row_cnt,
                                              enc_edge_W, enc_edge_b, pa1e2, hb1, pa2e2, hb2, jac2);

    size_t lds_nm = (4*768 + 4*512) * sizeof(float);
    k_node_mlp<<<1024, 256, lds_nm, stream>>>(jac1, jac2, sumsp, enc2_W, enc2_b,
                                              jW1, jb1, jW2, jb2, jac1);
    k_node_mlp<<<1024, 256, lds_nm, stream>>>(hjp, hjm, sumsp, enc2_W, enc2_b,
                                              sW1, sb1, sW2, sb2, hjp);

    size_t lds_nf = (4*1024 + 4*512) * sizeof(float);
    k_node_final<<<1024, 256, lds_nf, stream>>>(x, enc_node_W, enc_node_b,
                                                jac1, hjp,
                                                batch, glob_attr, enc_glob_W, enc_glob_b,
                                                nW1, nb1, nW2, nb2, decW, decb,
                                                node_attr, (float*)d_out);
}

// Round 11
// 2316.951 us; speedup vs baseline: 1.3180x; 1.0397x over previous
//
#include <hip/hip_runtime.h>
#include <hip/hip_fp16.h>
#include <math.h>

#define BN 50000
#define BE 800000
#define CHUNK 104              // target edges per wave
#define NWAVES 7693            // ceil(BE/CHUNK)

typedef _Float16 h2 __attribute__((ext_vector_type(2)));
typedef _Float16 h4 __attribute__((ext_vector_type(4)));
typedef float    f4 __attribute__((ext_vector_type(4)));

__device__ __forceinline__ float relu_f(float v) { return fmaxf(v, 0.0f); }
__device__ __forceinline__ float inv_clean(float s) {
    float q = 1.0f / s;
    return isfinite(q) ? q : 0.0f;
}
__device__ __forceinline__ float inv_clean_fast(float s) {
    float q = __builtin_amdgcn_rcpf(s);
    return isfinite(q) ? q : 0.0f;
}
__device__ __forceinline__ unsigned int h2u(h2 v) { union { h2 h; unsigned int u; } x; x.h = v; return x.u; }
__device__ __forceinline__ h2 uh2(unsigned int v) { union { unsigned int u; h2 h; } x; x.u = v; return x.h; }
__device__ __forceinline__ unsigned int packh2(float a, float b) {
    h2 h; h.x = (_Float16)a; h.y = (_Float16)b; return h2u(h);
}
__device__ __forceinline__ h4 u2h4(uint2 v) { union { uint2 u; h4 h; } x; x.u = v; return x.h; }

// ===========================================================================
// Weight packing (outputs in d_out head; k_node_final overwrites d_out last)
// ===========================================================================
// fp32 pair-pack rows r0..r0+63 of [*,128] (for k_tptmh)
__global__ __launch_bounds__(256) void k_pack_w1(
    const float* __restrict__ W, int r0, float4* __restrict__ dst)
{
    int t = blockIdx.x * 256 + threadIdx.x;
    if (t >= 2048) return;
    int j2 = t >> 6, l = t & 63;
    const float* ra = W + (size_t)(r0 + 2*j2) * 128 + 2*l;
    const float* rb = W + (size_t)(r0 + 2*j2 + 1) * 128 + 2*l;
    dst[t] = make_float4(ra[0], ra[1], rb[0], rb[1]);
}
// fp32 pack dW1 rows 0..127 for k_uvh
__global__ __launch_bounds__(256) void k_pack_uv(
    const float* __restrict__ dW1, float4* __restrict__ dst)
{
    int t = blockIdx.x * 256 + threadIdx.x;
    if (t >= 4096) return;
    int j = t >> 6, l = t & 63;
    float4 w;
    if (l < 32) w = ((const float4*)(dW1 + (size_t)j*128))[l];
    else        w = ((const float4*)(dW1 + (size_t)(64+j)*128))[l-32];
    dst[t] = w;
}
// MFMA A-fragment pack, layer-1: frag (n,s): A[i][k] = W[r0 + s*16 + k][n*16 + i]
__global__ __launch_bounds__(256) void k_pack_a1(
    const float* __restrict__ W, int r0, uint2* __restrict__ dst)
{
    int t = blockIdx.x * 256 + threadIdx.x;   // 2048 total (32 frags x 64 lanes)
    if (t >= 2048) return;
    int frag = t >> 6, l = t & 63;
    int n = frag >> 2, s = frag & 3;
    int i = l & 15, kq = l >> 4;
    size_t base = (size_t)(r0 + s*16 + kq*4) * 128 + n*16 + i;
    float w0 = W[base + 0*128];
    float w1 = W[base + 1*128];
    float w2 = W[base + 2*128];
    float w3 = W[base + 3*128];
    dst[t] = make_uint2(packh2(w0, w1), packh2(w2, w3));
}
// MFMA A-fragment pack, layer-2: frag (m,n): A[i][k] = W2[n*16 + k][m*16 + i]
__global__ __launch_bounds__(256) void k_pack_a2(
    const float* __restrict__ W2, uint2* __restrict__ dst)
{
    int t = blockIdx.x * 256 + threadIdx.x;   // 2048 total
    if (t >= 2048) return;
    int frag = t >> 6, l = t & 63;
    int m = frag >> 3, n = frag & 7;
    int i = l & 15, kq = l >> 4;
    size_t base = (size_t)(n*16 + kq*4) * 64 + m*16 + i;
    float w0 = W2[base + 0*64];
    float w1 = W2[base + 1*64];
    float w2 = W2[base + 2*64];
    float w3 = W2[base + 3*64];
    dst[t] = make_uint2(packh2(w0, w1), packh2(w2, w3));
}

// ===========================================================================
// CSR-ish build
// ===========================================================================
__global__ __launch_bounds__(256) void k_hist(
    const int* __restrict__ ei, int* __restrict__ rc, int* __restrict__ cc)
{
    int e = blockIdx.x * 256 + threadIdx.x;
    if (e >= BE) return;
    atomicAdd(&rc[ei[e]], 1);
    atomicAdd(&cc[ei[BE + e]], 1);
}

__global__ __launch_bounds__(1024) void k_scan(
    const int* __restrict__ cntR, int* __restrict__ hdR,
    const int* __restrict__ cntC, int* __restrict__ hdC)
{
    __shared__ int s[1024];
    const int* cnt; int* hd;
    if (blockIdx.x == 0) { cnt = cntR; hd = hdR; }
    else                 { cnt = cntC; hd = hdC; }
    int t = threadIdx.x;
    int base = t * 49;
    int sum = 0;
    for (int i = 0; i < 49; i++) {
        int idx = base + i;
        sum += (idx < BN) ? cnt[idx] : 0;
    }
    s[t] = sum;
    __syncthreads();
    for (int o = 1; o < 1024; o <<= 1) {
        int v = (t >= o) ? s[t - o] : 0;
        __syncthreads();
        s[t] += v;
        __syncthreads();
    }
    int run = s[t] - sum;
    for (int i = 0; i < 49; i++) {
        int idx = base + i;
        if (idx < BN) { hd[idx] = run; run += cnt[idx]; }
    }
}

__global__ __launch_bounds__(256) void k_scatter2(
    const int* __restrict__ ei, const float* __restrict__ ea,
    int* __restrict__ rhd, int* __restrict__ chd,
    int4* __restrict__ rs, int4* __restrict__ cs)
{
    int e = blockIdx.x * 256 + threadIdx.x;
    if (e >= BE) return;
    int r = ei[e], c = ei[BE + e];
    float2 s = ((const float2*)ea)[e];
    int s0 = __float_as_int(s.x), s1 = __float_as_int(s.y);
    int p1 = atomicAdd(&rhd[r], 1);
    rs[p1] = make_int4(r, c, s0, s1);
    int p2 = atomicAdd(&chd[c], 1);
    cs[p2] = make_int4(c, r, s0, s1);
}

// sumsp from sorted records (hd = end offsets after scatter)
__global__ __launch_bounds__(256) void k_sumsp2(
    const int4* __restrict__ rs, const int* __restrict__ rhd, const int* __restrict__ rcnt,
    const int4* __restrict__ cs, const int* __restrict__ chd, const int* __restrict__ ccnt,
    float* __restrict__ sumsp)
{
    int n = blockIdx.x * 256 + threadIdx.x;
    if (n >= BN) return;
    float s0 = 0.f, s1 = 0.f;
    int e1 = rhd[n], e0 = e1 - rcnt[n];
    for (int j = e0; j < e1; j++) {
        int4 rec = rs[j];
        s0 += __int_as_float(rec.z); s1 += __int_as_float(rec.w);
    }
    e1 = chd[n]; e0 = e1 - ccnt[n];
    for (int j = e0; j < e1; j++) {
        int4 rec = cs[j];
        s0 += __int_as_float(rec.z); s1 += __int_as_float(rec.w);
    }
    sumsp[2*n]   = s0;
    sumsp[2*n+1] = s1;
}

// Node-aligned wave partition: lb[w] = first node whose start offset >= w*CHUNK.
__global__ __launch_bounds__(256) void k_part(
    const int* __restrict__ rhd, const int* __restrict__ rcnt, int* __restrict__ lbr,
    const int* __restrict__ chd, const int* __restrict__ ccnt, int* __restrict__ lbc)
{
    int t = blockIdx.x * 256 + threadIdx.x;
    if (t >= 2 * (NWAVES + 1)) return;
    int which = (t > NWAVES) ? 1 : 0;
    int w = t - which * (NWAVES + 1);
    const int* hd  = which ? chd  : rhd;
    const int* cnt = which ? ccnt : rcnt;
    int* lb        = which ? lbc  : lbr;
    if (w == NWAVES) { lb[NWAVES] = BN; return; }
    int target = w * CHUNK;
    int lo = 0, hi = BN;
    while (lo < hi) {
        int mid = (lo + hi) >> 1;
        int s = hd[mid] - cnt[mid];       // start offset of node mid
        if (s >= target) hi = mid; else lo = mid + 1;
    }
    lb[w] = lo;
}

// ===========================================================================
// k_uvh: fused node-enc + uv GEMM; outputs u,v in fp16
// ===========================================================================
__global__ __launch_bounds__(256, 6) void k_uvh(
    const float* __restrict__ x,
    const float* __restrict__ enW, const float* __restrict__ enB,
    const float4* __restrict__ guv,
    __half* __restrict__ u_h, __half* __restrict__ v_h)
{
    extern __shared__ float lds[];
    const int wid = threadIdx.x >> 6, l = threadIdx.x & 63;
    float4* xb4 = (float4*)(lds + wid * 512);
    const int gw = blockIdx.x * 4 + wid;
    const int nw = gridDim.x * 4;

    const int jj = l & 31;
    const float w0a = enW[jj],    w0b = enW[64+jj],  b0 = enB[jj];
    const float w1a = enW[jj+32], w1b = enW[96+jj],  b1 = enB[jj+32];

    for (int g = gw; g < BN/8; g += nw) {
        const int n0 = g * 8;
        const int q = l >> 5;
        {
            float2 xa = ((const float2*)x)[n0 + q*4 + 0];
            float2 xb = ((const float2*)x)[n0 + q*4 + 1];
            float2 xc = ((const float2*)x)[n0 + q*4 + 2];
            float2 xd = ((const float2*)x)[n0 + q*4 + 3];
            float4 p0, p1;
            p0.x = relu_f(fmaf(xa.x, w0a, fmaf(xa.y, w0b, b0)));
            p0.y = relu_f(fmaf(xb.x, w0a, fmaf(xb.y, w0b, b0)));
            p0.z = relu_f(fmaf(xc.x, w0a, fmaf(xc.y, w0b, b0)));
            p0.w = relu_f(fmaf(xd.x, w0a, fmaf(xd.y, w0b, b0)));
            p1.x = relu_f(fmaf(xa.x, w1a, fmaf(xa.y, w1b, b1)));
            p1.y = relu_f(fmaf(xb.x, w1a, fmaf(xb.y, w1b, b1)));
            p1.z = relu_f(fmaf(xc.x, w1a, fmaf(xc.y, w1b, b1)));
            p1.w = relu_f(fmaf(xd.x, w1a, fmaf(xd.y, w1b, b1)));
            xb4[jj*2 + q]      = p0;
            xb4[(jj+32)*2 + q] = p1;
        }
        float4 acc[8];
        #pragma unroll
        for (int e = 0; e < 8; e++) acc[e] = make_float4(0,0,0,0);
        #pragma unroll 8
        for (int j = 0; j < 64; j++) {
            float4 wq = guv[j*64 + l];
            float4 xa = xb4[j*2 + 0];
            float4 xc = xb4[j*2 + 1];
            acc[0].x = fmaf(xa.x, wq.x, acc[0].x); acc[0].y = fmaf(xa.x, wq.y, acc[0].y);
            acc[0].z = fmaf(xa.x, wq.z, acc[0].z); acc[0].w = fmaf(xa.x, wq.w, acc[0].w);
            acc[1].x = fmaf(xa.y, wq.x, acc[1].x); acc[1].y = fmaf(xa.y, wq.y, acc[1].y);
            acc[1].z = fmaf(xa.y, wq.z, acc[1].z); acc[1].w = fmaf(xa.y, wq.w, acc[1].w);
            acc[2].x = fmaf(xa.z, wq.x, acc[2].x); acc[2].y = fmaf(xa.z, wq.y, acc[2].y);
            acc[2].z = fmaf(xa.z, wq.z, acc[2].z); acc[2].w = fmaf(xa.z, wq.w, acc[2].w);
            acc[3].x = fmaf(xa.w, wq.x, acc[3].x); acc[3].y = fmaf(xa.w, wq.y, acc[3].y);
            acc[3].z = fmaf(xa.w, wq.z, acc[3].z); acc[3].w = fmaf(xa.w, wq.w, acc[3].w);
            acc[4].x = fmaf(xc.x, wq.x, acc[4].x); acc[4].y = fmaf(xc.x, wq.y, acc[4].y);
            acc[4].z = fmaf(xc.x, wq.z, acc[4].z); acc[4].w = fmaf(xc.x, wq.w, acc[4].w);
            acc[5].x = fmaf(xc.y, wq.x, acc[5].x); acc[5].y = fmaf(xc.y, wq.y, acc[5].y);
            acc[5].z = fmaf(xc.y, wq.z, acc[5].z); acc[5].w = fmaf(xc.y, wq.w, acc[5].w);
            acc[6].x = fmaf(xc.z, wq.x, acc[6].x); acc[6].y = fmaf(xc.z, wq.y, acc[6].y);
            acc[6].z = fmaf(xc.z, wq.z, acc[6].z); acc[6].w = fmaf(xc.z, wq.w, acc[6].w);
            acc[7].x = fmaf(xc.w, wq.x, acc[7].x); acc[7].y = fmaf(xc.w, wq.y, acc[7].y);
            acc[7].z = fmaf(xc.w, wq.z, acc[7].z); acc[7].w = fmaf(xc.w, wq.w, acc[7].w);
        }
        __half* dst = (l < 32) ? (u_h + 4*l) : (v_h + 4*(l-32));
        #pragma unroll
        for (int e = 0; e < 8; e++) {
            __half2* p = (__half2*)(dst + (size_t)(n0+e)*128);
            p[0] = __floats2half2_rn(acc[e].x, acc[e].y);
            p[1] = __floats2half2_rn(acc[e].z, acc[e].w);
        }
    }
}

// ===========================================================================
// k_em<MODE>: MFMA edge kernel, 16 edges/batch. Round-11: layer-2 fused into
// the n-loop (hf_n consumed immediately by 4 accumulators) -> no hf[8] array,
// no scratch spills.
// ===========================================================================
template<int MODE>
__global__ __launch_bounds__(256, 4) void k_em(
    const int4* __restrict__ recs,
    const __half* __restrict__ A_h, const __half* __restrict__ B_h,
    const int* __restrict__ lb, const int* __restrict__ hd, const int* __restrict__ cnt,
    const float* __restrict__ ew, const float* __restrict__ ebv,
    const uint2* __restrict__ pa1, const float* __restrict__ b1g,
    const uint2* __restrict__ pa2, const float* __restrict__ b2g,
    float* __restrict__ out)
{
    extern __shared__ float lds[];
    const int l = threadIdx.x & 63, wid = threadIdx.x >> 6;
    float* sbuf = lds + wid * (16 * 68);

    const int wave = blockIdx.x * 4 + wid;
    if (wave >= NWAVES) return;
    const int nlo = lb[wave], nhi = lb[wave + 1];
    if (nlo >= nhi) return;
    const int eb = hd[nlo] - cnt[nlo];
    const int ee = (nhi < BN) ? (hd[nhi] - cnt[nhi]) : BE;
    if (eb >= ee) return;

    const int kq = l >> 4, li = l & 15;
    const float b2r = b2g[l];

    float acc = 0.f;
    int cur = -1;

    for (int i0 = eb; i0 < ee; i0 += 16) {
        const int nact = min(16, ee - i0);
        int4 rec = recs[i0 + min(li, nact - 1)];
        const int mykey = rec.x, myoth = rec.y;
        float q0 = __int_as_float(rec.z), q1 = __int_as_float(rec.w);
        if (MODE == 0) { q0 = inv_clean_fast(q0); q1 = inv_clean_fast(q1); }

        // B1 fragments: x[ch = s*16 + kq*4 + r] of my edge (li)
        h4 xb[4];
        #pragma unroll
        for (int s = 0; s < 4; s++) {
            const float4 wA = *(const float4*)(ew + s*16 + kq*4);
            const float4 wB = *(const float4*)(ew + 64 + s*16 + kq*4);
            const float4 bb = *(const float4*)(ebv + s*16 + kq*4);
            h4 xv;
            xv[0] = (_Float16)relu_f(fmaf(q0, wA.x, fmaf(q1, wB.x, bb.x)));
            xv[1] = (_Float16)relu_f(fmaf(q0, wA.y, fmaf(q1, wB.y, bb.y)));
            xv[2] = (_Float16)relu_f(fmaf(q0, wA.z, fmaf(q1, wB.z, bb.z)));
            xv[3] = (_Float16)relu_f(fmaf(q0, wA.w, fmaf(q1, wB.w, bb.w)));
            xb[s] = xv;
        }

        // fused layer-1 -> layer-2: hf_n consumed immediately (no hf[8] array)
        f4 a2_0 = {0.f, 0.f, 0.f, 0.f};
        f4 a2_1 = {0.f, 0.f, 0.f, 0.f};
        f4 a2_2 = {0.f, 0.f, 0.f, 0.f};
        f4 a2_3 = {0.f, 0.f, 0.f, 0.f};
        #pragma unroll
        for (int n = 0; n < 8; n++) {
            f4 a1 = {0.f, 0.f, 0.f, 0.f};
            #pragma unroll
            for (int s = 0; s < 4; s++)
                a1 = __builtin_amdgcn_mfma_f32_16x16x16f16(
                        u2h4(pa1[(n*4 + s)*64 + l]), xb[s], a1, 0, 0, 0);
            const float4 b1q = *(const float4*)(b1g + n*16 + kq*4);
            float t0, t1, t2, t3;
            if (MODE == 0) {
                uint2 uu = *(const uint2*)(A_h + (size_t)mykey*128 + n*16 + kq*4);
                uint2 vv = *(const uint2*)(B_h + (size_t)myoth*128 + n*16 + kq*4);
                h2 ul = uh2(uu.x), uhh = uh2(uu.y), vl = uh2(vv.x), vhh = uh2(vv.y);
                t0 = a1[0] + b1q.x + (float)ul.x  + (float)vl.x;
                t1 = a1[1] + b1q.y + (float)ul.y  + (float)vl.y;
                t2 = a1[2] + b1q.z + (float)uhh.x + (float)vhh.x;
                t3 = a1[3] + b1q.w + (float)uhh.y + (float)vhh.y;
            } else {
                uint2 tt = *(const uint2*)(A_h + (size_t)mykey*128 + n*16 + kq*4);
                h2 tl = uh2(tt.x), th = uh2(tt.y);
                t0 = a1[0] + b1q.x + (float)tl.x;
                t1 = a1[1] + b1q.y + (float)tl.y;
                t2 = a1[2] + b1q.z + (float)th.x;
                t3 = a1[3] + b1q.w + (float)th.y;
            }
            h4 hfn;
            hfn[0] = (_Float16)relu_f(t0);
            hfn[1] = (_Float16)relu_f(t1);
            hfn[2] = (_Float16)relu_f(t2);
            hfn[3] = (_Float16)relu_f(t3);
            a2_0 = __builtin_amdgcn_mfma_f32_16x16x16f16(u2h4(pa2[(0*8 + n)*64 + l]), hfn, a2_0, 0, 0, 0);
            a2_1 = __builtin_amdgcn_mfma_f32_16x16x16f16(u2h4(pa2[(1*8 + n)*64 + l]), hfn, a2_1, 0, 0, 0);
            a2_2 = __builtin_amdgcn_mfma_f32_16x16x16f16(u2h4(pa2[(2*8 + n)*64 + l]), hfn, a2_2, 0, 0, 0);
            a2_3 = __builtin_amdgcn_mfma_f32_16x16x16f16(u2h4(pa2[(3*8 + n)*64 + l]), hfn, a2_3, 0, 0, 0);
        }

        // D: edge=l&15, outch=(l>>4)*4+r+m*16 -> LDS transpose then merge
        *(float4*)(sbuf + li*68 + 0*16 + kq*4) = make_float4(a2_0[0], a2_0[1], a2_0[2], a2_0[3]);
        *(float4*)(sbuf + li*68 + 1*16 + kq*4) = make_float4(a2_1[0], a2_1[1], a2_1[2], a2_1[3]);
        *(float4*)(sbuf + li*68 + 2*16 + kq*4) = make_float4(a2_2[0], a2_2[1], a2_2[2], a2_2[3]);
        *(float4*)(sbuf + li*68 + 3*16 + kq*4) = make_float4(a2_3[0], a2_3[1], a2_3[2], a2_3[3]);

        // merge epilogue: lane = outch l, serial over edges (keys via readlane)
        #pragma unroll
        for (int e = 0; e < 16; e++) {
            if (e < nact) {
                int ke = __builtin_amdgcn_readlane(mykey, e);
                float val = sbuf[e*68 + l] + b2r;
                if (ke != cur) {
                    if (cur >= 0) out[(size_t)cur*64 + l] = acc;   // plain store
                    acc = 0.f;
                    cur = ke;
                }
                acc += val;
            }
        }
    }
    if (cur >= 0) out[(size_t)cur*64 + l] = acc;
}

// ===========================================================================
// k_tptmh: tp[n] = hjp[n] @ hW1[64:128,:], tm[n] = hjm[n] @ hW1[64:128,:]  (fp16 out)
// ===========================================================================
__global__ __launch_bounds__(256, 6) void k_tptmh(
    const float* __restrict__ hjp, const float* __restrict__ hjm,
    const float4* __restrict__ gtp,
    __half* __restrict__ tp_h, __half* __restrict__ tm_h)
{
    extern __shared__ float lds[];
    const int wid = threadIdx.x >> 6, l = threadIdx.x & 63;
    float4* xb4 = (float4*)(lds + wid * 512);
    const int gw = blockIdx.x * 4 + wid;
    const int nw = gridDim.x * 4;
    const int NG = BN/8;

    for (int vg = gw; vg < 2*NG; vg += nw) {
        const float* in = (vg < NG) ? hjp : hjm;
        __half*     out = (vg < NG) ? tp_h : tm_h;
        const int n0 = ((vg < NG) ? vg : vg - NG) * 8;
        const int q = l >> 5;
        #pragma unroll
        for (int r = 0; r < 2; r++) {
            int j = (l & 31) + 32*r;
            float v0 = in[(n0 + q*4 + 0)*64 + j];
            float v1 = in[(n0 + q*4 + 1)*64 + j];
            float v2 = in[(n0 + q*4 + 2)*64 + j];
            float v3 = in[(n0 + q*4 + 3)*64 + j];
            xb4[j*2 + q] = make_float4(v0, v1, v2, v3);
        }
        float a0[8] = {0,0,0,0,0,0,0,0}, a1[8] = {0,0,0,0,0,0,0,0};
        #pragma unroll 8
        for (int j2 = 0; j2 < 32; j2++) {
            float4 wq = gtp[j2*64 + l];
            float4 xa = xb4[(2*j2)*2 + 0];
            float4 xbv = xb4[(2*j2)*2 + 1];
            float4 xc = xb4[(2*j2+1)*2 + 0];
            float4 xd = xb4[(2*j2+1)*2 + 1];
            a0[0] = fmaf(xa.x, wq.x, fmaf(xc.x, wq.z, a0[0]));
            a1[0] = fmaf(xa.x, wq.y, fmaf(xc.x, wq.w, a1[0]));
            a0[1] = fmaf(xa.y, wq.x, fmaf(xc.y, wq.z, a0[1]));
            a1[1] = fmaf(xa.y, wq.y, fmaf(xc.y, wq.w, a1[1]));
            a0[2] = fmaf(xa.z, wq.x, fmaf(xc.z, wq.z, a0[2]));
            a1[2] = fmaf(xa.z, wq.y, fmaf(xc.z, wq.w, a1[2]));
            a0[3] = fmaf(xa.w, wq.x, fmaf(xc.w, wq.z, a0[3]));
            a1[3] = fmaf(xa.w, wq.y, fmaf(xc.w, wq.w, a1[3]));
            a0[4] = fmaf(xbv.x, wq.x, fmaf(xd.x, wq.z, a0[4]));
            a1[4] = fmaf(xbv.x, wq.y, fmaf(xd.x, wq.w, a1[4]));
            a0[5] = fmaf(xbv.y, wq.x, fmaf(xd.y, wq.z, a0[5]));
            a1[5] = fmaf(xbv.y, wq.y, fmaf(xd.y, wq.w, a1[5]));
            a0[6] = fmaf(xbv.z, wq.x, fmaf(xd.z, wq.z, a0[6]));
            a1[6] = fmaf(xbv.z, wq.y, fmaf(xd.z, wq.w, a1[6]));
            a0[7] = fmaf(xbv.w, wq.x, fmaf(xd.w, wq.z, a0[7]));
            a1[7] = fmaf(xbv.w, wq.y, fmaf(xd.w, wq.w, a1[7]));
        }
        #pragma unroll
        for (int e = 0; e < 8; e++) {
            *(__half2*)(out + (size_t)(n0+e)*128 + 2*l) = __floats2half2_rn(a0[e], a1[e]);
        }
    }
}

// ===========================================================================
// Node MLP kernels (fp32, weights streamed from global)
// ===========================================================================
__global__ __launch_bounds__(256, 4) void k_node_mlp(
    const float* __restrict__ A, const float* __restrict__ Bv,
    const float* __restrict__ sumsp,
    const float* __restrict__ e2w_g, const float* __restrict__ e2b_g,
    const float* __restrict__ W1g, const float* __restrict__ b1g,
    const float* __restrict__ W2g, const float* __restrict__ b2g,
    float* __restrict__ outp)
{
    extern __shared__ float lds[];
    const int wid = threadIdx.x >> 6, l = threadIdx.x & 63;
    float* xbuf = lds + wid * 768;
    float* hbuf = lds + 4*768 + wid * 512;

    const float ewl = e2w_g[l], ewl2 = e2w_g[64+l], ebl = e2b_g[l];
    const float bb0 = b1g[2*l], bb1 = b1g[2*l+1];
    const float bo = b2g[l];

    const int gw = blockIdx.x * 4 + wid;
    const int nw = gridDim.x * 4;

    for (int g = gw; g < BN/4; g += nw) {
        const int i0 = g * 4;
        float av[4], bv[4], iv[4];
        #pragma unroll
        for (int e = 0; e < 4; e++) {
            int i = i0 + e;
            av[e] = A[i*64 + l];
            bv[e] = Bv[i*64 + l];
            float q0 = inv_clean(sumsp[i*2+0]);
            float q1 = inv_clean(sumsp[i*2+1]);
            iv[e] = relu_f(fmaf(q0, ewl, fmaf(q1, ewl2, ebl)));
        }
        ((float4*)xbuf)[l]       = make_float4(av[0], av[1], av[2], av[3]);
        ((float4*)xbuf)[64 + l]  = make_float4(bv[0], bv[1], bv[2], bv[3]);
        ((float4*)xbuf)[128 + l] = make_float4(iv[0], iv[1], iv[2], iv[3]);

        float acc0[4] = {0,0,0,0}, acc1[4] = {0,0,0,0};
        #pragma unroll 8
        for (int j = 0; j < 192; j++) {
            float4 xv = ((const float4*)xbuf)[j];
            float2 wv = ((const float2*)(W1g + j*128))[l];
            acc0[0] = fmaf(xv.x, wv.x, acc0[0]);
            acc0[1] = fmaf(xv.y, wv.x, acc0[1]);
            acc0[2] = fmaf(xv.z, wv.x, acc0[2]);
            acc0[3] = fmaf(xv.w, wv.x, acc0[3]);
            acc1[0] = fmaf(xv.x, wv.y, acc1[0]);
            acc1[1] = fmaf(xv.y, wv.y, acc1[1]);
            acc1[2] = fmaf(xv.z, wv.y, acc1[2]);
            acc1[3] = fmaf(xv.w, wv.y, acc1[3]);
        }
        #pragma unroll
        for (int e = 0; e < 4; e++) {
            ((float2*)(hbuf + e*128))[l] = make_float2(relu_f(acc0[e]+bb0), relu_f(acc1[e]+bb1));
        }
        float o[4] = {0,0,0,0};
        #pragma unroll 8
        for (int k = 0; k < 128; k++) {
            float wv = W2g[k*64 + l];
            o[0] = fmaf(hbuf[0*128+k], wv, o[0]);
            o[1] = fmaf(hbuf[1*128+k], wv, o[1]);
            o[2] = fmaf(hbuf[2*128+k], wv, o[2]);
            o[3] = fmaf(hbuf[3*128+k], wv, o[3]);
        }
        #pragma unroll
        for (int e = 0; e < 4; e++) outp[(i0+e)*64 + l] = o[e] + bo;
    }
}

__global__ __launch_bounds__(256, 4) void k_node_final(
    const float* __restrict__ x,
    const float* __restrict__ enW, const float* __restrict__ enB,
    const float* __restrict__ jacv, const float* __restrict__ hessv,
    const int* __restrict__ batch, const float* __restrict__ ga,
    const float* __restrict__ gw_g, const float* __restrict__ gb_g,
    const float* __restrict__ nW1, const float* __restrict__ nb1,
    const float* __restrict__ nW2, const float* __restrict__ nb2,
    const float* __restrict__ decW, const float* __restrict__ decb,
    const float* __restrict__ node_attr, float* __restrict__ outp)
{
    extern __shared__ float lds[];
    const int wid = threadIdx.x >> 6, l = threadIdx.x & 63;
    float* xbuf = lds + wid * 1024;
    float* hbuf = lds + 4*1024 + wid * 512;

    const float gwl = gw_g[l], gwl2 = gw_g[64+l], gbl = gb_g[l];
    const float enw0 = enW[l], enw1 = enW[64+l], enb = enB[l];
    const float bb0 = nb1[2*l], bb1 = nb1[2*l+1];
    const float bo = nb2[l];

    const int gwv = blockIdx.x * 4 + wid;
    const int nw = gridDim.x * 4;

    for (int g = gwv; g < BN/4; g += nw) {
        const int i0 = g * 4;
        float ne[4], jv[4], ge[4], hv[4];
        #pragma unroll
        for (int e = 0; e < 4; e++) {
            int i = i0 + e;
            ne[e] = relu_f(fmaf(x[i*2], enw0, fmaf(x[i*2+1], enw1, enb)));
            jv[e] = jacv[i*64 + l];
            hv[e] = hessv[i*64 + l];
            int gi = batch[i];
            ge[e] = relu_f(fmaf(ga[gi*2], gwl, fmaf(ga[gi*2+1], gwl2, gbl)));
        }
        ((float4*)xbuf)[l]       = make_float4(ne[0], ne[1], ne[2], ne[3]);
        ((float4*)xbuf)[64 + l]  = make_float4(jv[0], jv[1], jv[2], jv[3]);
        ((float4*)xbuf)[128 + l] = make_float4(ge[0], ge[1], ge[2], ge[3]);
        ((float4*)xbuf)[192 + l] = make_float4(hv[0], hv[1], hv[2], hv[3]);

        float acc0[4] = {0,0,0,0}, acc1[4] = {0,0,0,0};
        #pragma unroll 8
        for (int j = 0; j < 256; j++) {
            float4 xv = ((const float4*)xbuf)[j];
            float2 wv = ((const float2*)(nW1 + j*128))[l];
            acc0[0] = fmaf(xv.x, wv.x, acc0[0]);
            acc0[1] = fmaf(xv.y, wv.x, acc0[1]);
            acc0[2] = fmaf(xv.z, wv.x, acc0[2]);
            acc0[3] = fmaf(xv.w, wv.x, acc0[3]);
            acc1[0] = fmaf(xv.x, wv.y, acc1[0]);
            acc1[1] = fmaf(xv.y, wv.y, acc1[1]);
            acc1[2] = fmaf(xv.z, wv.y, acc1[2]);
            acc1[3] = fmaf(xv.w, wv.y, acc1[3]);
        }
        #pragma unroll
        for (int e = 0; e < 4; e++) {
            ((float2*)(hbuf + e*128))[l] = make_float2(relu_f(acc0[e]+bb0), relu_f(acc1[e]+bb1));
        }
        float o[4] = {0,0,0,0};
        #pragma unroll 8
        for (int k = 0; k < 128; k++) {
            float wv = nW2[k*64 + l];
            o[0] = fmaf(hbuf[0*128+k], wv, o[0]);
            o[1] = fmaf(hbuf[1*128+k], wv, o[1]);
            o[2] = fmaf(hbuf[2*128+k], wv, o[2]);
            o[3] = fmaf(hbuf[3*128+k], wv, o[3]);
        }
        #pragma unroll
        for (int e = 0; e < 4; e++) hbuf[e*128 + l] = o[e] + bo;

        int e2 = l >> 4, sub = l & 15, j2 = sub >> 3, part = sub & 7;
        float s = 0.0f;
        #pragma unroll
        for (int kk = 0; kk < 8; kk++) {
            int k = part*8 + kk;
            s = fmaf(hbuf[e2*128 + k], decW[k*2 + j2], s);
        }
        s += __shfl_xor(s, 1);
        s += __shfl_xor(s, 2);
        s += __shfl_xor(s, 4);
        if (part == 0) {
            int i = i0 + e2;
            outp[i*2 + j2] = (s + decb[j2]) * node_attr[i*2 + j2];
        }
    }
}

// ===========================================================================
extern "C" void kernel_launch(void* const* d_in, const int* in_sizes, int n_in,
                              void* d_out, int out_size, void* d_ws, size_t ws_size,
                              hipStream_t stream) {
    const float* x          = (const float*)d_in[0];
    const int*   ei         = (const int*)  d_in[1];
    const int*   batch      = (const int*)  d_in[2];
    const float* node_attr  = (const float*)d_in[3];
    const float* edge_attr  = (const float*)d_in[4];
    const float* glob_attr  = (const float*)d_in[5];
    const float* enc_node_W = (const float*)d_in[6];
    const float* enc_node_b = (const float*)d_in[7];
    const float* enc_edge_W = (const float*)d_in[8];
    const float* enc_edge_b = (const float*)d_in[9];
    const float* enc_glob_W = (const float*)d_in[10];
    const float* enc_glob_b = (const float*)d_in[11];
    const float* enc2_W     = (const float*)d_in[12];
    const float* enc2_b     = (const float*)d_in[13];
    const float* dW1 = (const float*)d_in[14]; const float* db1 = (const float*)d_in[15];
    const float* dW2 = (const float*)d_in[16]; const float* db2 = (const float*)d_in[17];
    const float* hW1 = (const float*)d_in[18]; const float* hb1 = (const float*)d_in[19];
    const float* hW2 = (const float*)d_in[20]; const float* hb2 = (const float*)d_in[21];
    const float* jW1 = (const float*)d_in[22]; const float* jb1 = (const float*)d_in[23];
    const float* jW2 = (const float*)d_in[24]; const float* jb2 = (const float*)d_in[25];
    const float* sW1 = (const float*)d_in[26]; const float* sb1 = (const float*)d_in[27];
    const float* sW2 = (const float*)d_in[28]; const float* sb2 = (const float*)d_in[29];
    const float* nW1 = (const float*)d_in[30]; const float* nb1 = (const float*)d_in[31];
    const float* nW2 = (const float*)d_in[32]; const float* nb2 = (const float*)d_in[33];
    const float* decW = (const float*)d_in[34]; const float* decb = (const float*)d_in[35];

    float* ws = (float*)d_ws;
    int4*   rs    = (int4*)ws;                           // 3.2M fl
    int4*   cs    = (int4*)(ws + 3200000);               // 3.2M fl
    __half* u_h   = (__half*)(ws + 6400000);             // 3.2M fl (-> tp_h)
    __half* v_h   = (__half*)(ws + 9600000);             // 3.2M fl (-> tm_h)
    float*  hjp   = ws + 12800000;                       // 3.2M (-> hess)
    float*  hjm   = ws + 16000000;                       // 3.2M
    float*  jac1  = ws + 19200000;                       // 3.2M (-> jac)
    float*  jac2  = ws + 22400000;                       // 3.2M
    float*  sumsp = ws + 25600000;                       // 100K
    int*    row_cnt = (int*)(ws + 25700000);             // 50176
    int*    col_cnt = row_cnt + 50176;                   // 50176
    int*    row_hd  = col_cnt + 50176;                   // 50048
    int*    col_hd  = row_hd + 50048;                    // 50048
    int*    lbr     = col_hd + 50048;                    // 7694
    int*    lbc     = lbr + 7694;                        // 7694

    // packed weights in d_out head (40,960 floats <= out_size 100,000)
    float* scratch = (float*)d_out;
    float4* puv   = (float4*)(scratch);                  // 16384 f
    float4* ptp   = (float4*)(scratch + 16384);          // 8192 f
    uint2*  pa1e1 = (uint2*)(scratch + 24576);           // 4096 f
    uint2*  pa2e1 = (uint2*)(scratch + 28672);           // 4096 f
    uint2*  pa1e2 = (uint2*)(scratch + 32768);           // 4096 f
    uint2*  pa2e2 = (uint2*)(scratch + 36864);           // 4096 f

    hipMemsetAsync(hjp, 0, (size_t)12800000*sizeof(float), stream);
    hipMemsetAsync(row_cnt, 0, (size_t)(2*50176)*sizeof(int), stream);

    k_pack_uv<<<16, 256, 0, stream>>>(dW1, puv);
    k_pack_w1<<<8, 256, 0, stream>>>(hW1, 64, ptp);
    k_pack_a1<<<8, 256, 0, stream>>>(dW1, 128, pa1e1);   // ise block of dW1
    k_pack_a2<<<8, 256, 0, stream>>>(dW2, pa2e1);
    k_pack_a1<<<8, 256, 0, stream>>>(hW1, 0, pa1e2);     // se block of hW1
    k_pack_a2<<<8, 256, 0, stream>>>(hW2, pa2e2);

    // u,v (fp16) from fused node-enc + GEMM
    k_uvh<<<1563, 256, 2048*4, stream>>>(x, enc_node_W, enc_node_b, puv, u_h, v_h);

    // sorted edge records + node-aligned wave partition
    k_hist<<<3125, 256, 0, stream>>>(ei, row_cnt, col_cnt);
    k_scan<<<2, 1024, 0, stream>>>(row_cnt, row_hd, col_cnt, col_hd);
    k_scatter2<<<3125, 256, 0, stream>>>(ei, edge_attr, row_hd, col_hd, rs, cs);
    k_sumsp2<<<196, 256, 0, stream>>>(rs, row_hd, row_cnt, cs, col_hd, col_cnt, sumsp);
    k_part<<<61, 256, 0, stream>>>(row_hd, row_cnt, lbr, col_hd, col_cnt, lbc);

    const int E_BLOCKS = (NWAVES + 3) / 4;               // 1924
    const size_t lds_e = 4 * 16 * 68 * sizeof(float);    // 17408 B

    // pass 1: MFMA one-sided twins, plain stores
    k_em<0><<<E_BLOCKS, 256, lds_e, stream>>>(rs, u_h, v_h, lbr, row_hd, row_cnt,
                                              enc2_W, enc2_b, pa1e1, db1, pa2e1, db2, hjp);
    k_em<0><<<E_BLOCKS, 256, lds_e, stream>>>(cs, v_h, u_h, lbc, col_hd, col_cnt,
                                              enc2_W, enc2_b, pa1e1, db1, pa2e1, db2, hjm);

    // tp,tm (fp16) overwrite u_h,v_h
    k_tptmh<<<1536, 256, 2048*4, stream>>>(hjp, hjm, ptp, u_h, v_h);

    // pass 2: col-sorted -> jac1 (tp), row-sorted -> jac2 (tm)
    k_em<1><<<E_BLOCKS, 256, lds_e, stream>>>(cs, u_h, u_h, lbc, col_hd, col_cnt,
                                              enc_edge_W, enc_edge_b, pa1e2, hb1, pa2e2, hb2, jac1);
    k_em<1><<<E_BLOCKS, 256, lds_e, stream>>>(rs, v_h, v_h, lbr, row_hd, row_cnt,
                                              enc_edge_W, enc_edge_b, pa1e2, hb1, pa2e2, hb2, jac2);

    size_t lds_nm = (4*768 + 4*512) * sizeof(float);
    k_node_mlp<<<1024, 256, lds_nm, stream>>>(jac1, jac2, sumsp, enc2_W, enc2_b,
                                              jW1, jb1, jW2, jb2, jac1);
    k_node_mlp<<<1024, 256, lds_nm, stream>>>(hjp, hjm, sumsp, enc2_W, enc2_b,
                                              sW1, sb1, sW2, sb2, hjp);

    size_t lds_nf = (4*1024 + 4*512) * sizeof(float);
    k_node_final<<<1024, 256, lds_nf, stream>>>(x, enc_node_W, enc_node_b,
                                                jac1, hjp,
                                                batch, glob_attr, enc_glob_W, enc_glob_b,
                                                nW1, nb1, nW2, nb2, decW, decb,
                                                node_attr, (float*)d_out);
}